// Round 6
// baseline (344.550 us; speedup 1.0000x reference)
//
#include <hip/hip_runtime.h>
#include <hip/hip_bf16.h>

#define BB 8
#define NN 2048
#define MM 2048
#define DD 512

typedef __attribute__((ext_vector_type(8))) short bf16x8;
typedef __attribute__((ext_vector_type(4))) float f32x4;
typedef __attribute__((ext_vector_type(16))) float f32x16;
typedef __attribute__((ext_vector_type(8))) unsigned short u16x8;

__device__ __forceinline__ unsigned short f2bf(float x){
  unsigned int u = __float_as_uint(x);
  u += 0x7fffu + ((u>>16)&1u);   // round-to-nearest-even
  return (unsigned short)(u>>16);
}
__device__ __forceinline__ float bf2f(unsigned short h){
  return __uint_as_float(((unsigned int)h)<<16);
}
__device__ __forceinline__ f32x4 mfma16(bf16x8 a, bf16x8 b, f32x4 c){
  return __builtin_amdgcn_mfma_f32_16x16x32_bf16(a, b, c, 0, 0, 0);
}
__device__ __forceinline__ f32x16 mfma32(bf16x8 a, bf16x8 b, f32x16 c){
  return __builtin_amdgcn_mfma_f32_32x32x16_bf16(a, b, c, 0, 0, 0);
}

// async global->LDS, 16B per lane; LDS dest is wave-uniform base + lane*16
#define GLD16(gp, lp) __builtin_amdgcn_global_load_lds( \
    (const __attribute__((address_space(1))) void*)(gp), \
    (__attribute__((address_space(3))) void*)(lp), 16, 0, 0)

// wait until <= n vector-memory ops outstanding (lgkm/exp ignored)
#define WAITVM(n) __builtin_amdgcn_s_waitcnt(0xF70 | (n))

// batch->XCD swizzle: flat id f -> bz = f&7 (XCD presumed f%8), bijective
// (requires gridDim.z == 8)
__device__ __forceinline__ void swz_xyz(int& bn, int& bm, int& bz){
  int f = ((int)blockIdx.z * (int)gridDim.y + (int)blockIdx.y) * (int)gridDim.x
        + (int)blockIdx.x;
  bz = f & 7;
  int r = f >> 3;
  bn = r % (int)gridDim.x;
  bm = r / (int)gridDim.x;
}

// ---------------------------------------------------------------------------
// split2: f32 -> hi/lo bf16 (lo==nullptr -> hi only), float4-vectorized
// ---------------------------------------------------------------------------
__global__ __launch_bounds__(256) void split2_kernel(const float* __restrict__ in,
    unsigned short* __restrict__ hi, unsigned short* __restrict__ lo, int n4){
  int i = blockIdx.x*256 + threadIdx.x;
  const int stride = gridDim.x*256;
  for (; i < n4; i += stride){
    float4 v = ((const float4*)in)[i];
    ushort4 h; h.x=f2bf(v.x); h.y=f2bf(v.y); h.z=f2bf(v.z); h.w=f2bf(v.w);
    ((ushort4*)hi)[i] = h;
    if (lo){
      ushort4 l;
      l.x=f2bf(v.x-bf2f(h.x)); l.y=f2bf(v.y-bf2f(h.y));
      l.z=f2bf(v.z-bf2f(h.z)); l.w=f2bf(v.w-bf2f(h.w));
      ((ushort4*)lo)[i] = l;
    }
  }
}

// ---------------------------------------------------------------------------
// K0: At[j][i] = sum_e Wq[e][i] * Wk[e][j], written split hi/lo bf16
// ---------------------------------------------------------------------------
__global__ __launch_bounds__(256) void at_kernel(const float* __restrict__ Wq,
                                                 const float* __restrict__ Wk,
                                                 unsigned short* __restrict__ atHi,
                                                 unsigned short* __restrict__ atLo){
  const int i0 = blockIdx.x * 32, j0 = blockIdx.y * 32;
  __shared__ float q_s[32][33];
  __shared__ float k_s[32][33];
  const int t = threadIdx.x;
  const int tx = t & 15, ty = t >> 4;
  float acc[2][2] = {{0.f,0.f},{0.f,0.f}};
  for (int e0 = 0; e0 < DD; e0 += 32){
    __syncthreads();
#pragma unroll
    for (int p = 0; p < 4; ++p){
      int idx = t + 256*p;
      int e = idx >> 5, c = idx & 31;
      q_s[e][c] = Wq[(size_t)(e0+e)*DD + i0 + c];
      k_s[e][c] = Wk[(size_t)(e0+e)*DD + j0 + c];
    }
    __syncthreads();
#pragma unroll 8
    for (int e = 0; e < 32; ++e){
      float q0 = q_s[e][2*tx], q1 = q_s[e][2*tx+1];
      float k0 = k_s[e][2*ty], k1 = k_s[e][2*ty+1];
      acc[0][0] += k0*q0; acc[0][1] += k0*q1;
      acc[1][0] += k1*q0; acc[1][1] += k1*q1;
    }
  }
#pragma unroll
  for (int a = 0; a < 2; ++a)
#pragma unroll
    for (int b = 0; b < 2; ++b){
      float v = acc[a][b];
      size_t idx = (size_t)(j0 + 2*ty + a)*DD + i0 + 2*tx + b;
      unsigned short h = f2bf(v);
      atHi[idx] = h;
      atLo[idx] = f2bf(v - bf2f(h));
    }
}

// c2[d] = sum_e bq[e] * Wk[e][d]
__global__ __launch_bounds__(256) void c2_kernel(const float* __restrict__ bq,
                                                 const float* __restrict__ Wk,
                                                 float* __restrict__ c2){
  int d = blockIdx.x * 256 + threadIdx.x;
  float a = 0.f;
  for (int e = 0; e < DD; ++e) a += bq[e] * Wk[(size_t)e*DD + d];
  c2[d] = a;
}

// s[b*M+m] = dot(camera[b,m,:], c2)
__global__ __launch_bounds__(64) void s_kernel(const float* __restrict__ cam,
                                               const float* __restrict__ c2,
                                               float* __restrict__ svec){
  size_t row = blockIdx.x;
  const float* y = cam + row * DD;
  int l = threadIdx.x;
  float a = 0.f;
#pragma unroll
  for (int i = 0; i < 8; ++i) a += y[l + 64*i] * c2[l + 64*i];
  for (int o = 32; o; o >>= 1) a += __shfl_xor(a, o);
  if (l == 0) svec[row] = a;
}

// ---------------------------------------------------------------------------
// scores x3 GEMM, deep-pipelined:
//   O[row,col] = conf[row]*(sum_k T[row,k]*cam[col,k] + svec[col])
// Tile 256x256, BK=16, 8 waves (2Mx4N), wave tile 128x64 as 4x2 frags of
// 32x32x16 MFMA, x3 (hh+hl+lh).  LDS = 4 arrays x 4 buffers x [256][16]
// = 128KB.  3-tiles-ahead global_load_lds pipeline, counted vmcnt (never 0
// until the tail), ONE barrier per K-tile.  RACE-SAFE ordering:
//   WAITVM(8) ; s_barrier ; STAGE(tt+3) ; COMPUTE(tt)
// The barrier certifies (a) every wave's tile-tt loads landed (each wave
// drained to 8 outstanding = tiles tt+1,tt+2 only) and (b) every wave
// finished COMPUTE(tt-1), so STAGE may overwrite buffer (tt-1)&3.
// Bank-conflict-free chunk swizzle c^=(row&1) on both source and read sides.
// ---------------------------------------------------------------------------
__global__ __launch_bounds__(512, 2) void gemm_scores(
    const unsigned short* __restrict__ Thi, const unsigned short* __restrict__ Tlo,
    const unsigned short* __restrict__ camHi, const unsigned short* __restrict__ camLo,
    float* __restrict__ O,
    const float* __restrict__ conf, const float* __restrict__ svec)
{
  __shared__ unsigned short Ah[4][256][16];
  __shared__ unsigned short Al[4][256][16];
  __shared__ unsigned short Bh[4][256][16];
  __shared__ unsigned short Bl[4][256][16];

  int bn, bm, bz; swz_xyz(bn, bm, bz);     // grid (8,8,8)
  const int t = threadIdx.x;
  const int lane = t & 63, w = t >> 6;
  const int wr = w >> 2, wc = w & 3;       // wave tile: rows wr*128, cols wc*64

  // ---- read-side indices: row = base32 + (lane&31), stored chunk =
  //      (lane>>5) ^ (row&1) = (lane>>5) ^ (lane&1)   [base32 is even]
  const int l31 = lane & 31;
  const int co  = (((lane >> 5) ^ (lane & 1)) << 3);   // ushort offset in row

  // ---- staging: wave w stages rows [w*32, w*32+32) of each array per tile.
  //      lane i writes LDS row w*32+(i>>1), stored chunk (i&1); its global
  //      source is logical chunk (i&1)^((i>>1)&1)  (inverse swizzle).
  const int lrow = (w << 5) + (lane >> 1);
  const int koff = (((lane & 1) ^ ((lane >> 1) & 1)) << 3);
  const size_t offA = (size_t)bz*((size_t)NN*DD) + ((size_t)bm*256 + lrow)*DD + koff;
  const size_t offB = (size_t)bz*((size_t)MM*DD) + ((size_t)bn*256 + lrow)*DD + koff;
  const unsigned short* gAh = Thi   + offA;
  const unsigned short* gAl = Tlo   + offA;
  const unsigned short* gBh = camHi + offB;
  const unsigned short* gBl = camLo + offB;

#define STAGE(bufi, kofs) do {                       \
    GLD16(gAh + (kofs), &Ah[bufi][w<<5][0]);         \
    GLD16(gAl + (kofs), &Al[bufi][w<<5][0]);         \
    GLD16(gBh + (kofs), &Bh[bufi][w<<5][0]);         \
    GLD16(gBl + (kofs), &Bl[bufi][w<<5][0]);         \
  } while(0)

  f32x16 acc[4][2];
#pragma unroll
  for (int m = 0; m < 4; ++m)
#pragma unroll
    for (int n = 0; n < 2; ++n){
      f32x16 z = {0.f,0.f,0.f,0.f,0.f,0.f,0.f,0.f,0.f,0.f,0.f,0.f,0.f,0.f,0.f,0.f};
      acc[m][n] = z;
    }

#define COMPUTE(bufi) do {                                                     \
    bf16x8 b0h = *(const bf16x8*)&Bh[bufi][(wc<<6) +  0 + l31][co];            \
    bf16x8 b0l = *(const bf16x8*)&Bl[bufi][(wc<<6) +  0 + l31][co];            \
    bf16x8 b1h = *(const bf16x8*)&Bh[bufi][(wc<<6) + 32 + l31][co];            \
    bf16x8 b1l = *(const bf16x8*)&Bl[bufi][(wc<<6) + 32 + l31][co];            \
    bf16x8 a0h = *(const bf16x8*)&Ah[bufi][(wr<<7) +  0 + l31][co];            \
    bf16x8 a0l = *(const bf16x8*)&Al[bufi][(wr<<7) +  0 + l31][co];            \
    bf16x8 a1h = *(const bf16x8*)&Ah[bufi][(wr<<7) + 32 + l31][co];            \
    bf16x8 a1l = *(const bf16x8*)&Al[bufi][(wr<<7) + 32 + l31][co];            \
    __builtin_amdgcn_s_setprio(1);                                             \
    acc[0][0] = mfma32(a0h, b0h, acc[0][0]);                                   \
    acc[0][1] = mfma32(a0h, b1h, acc[0][1]);                                   \
    acc[1][0] = mfma32(a1h, b0h, acc[1][0]);                                   \
    acc[1][1] = mfma32(a1h, b1h, acc[1][1]);                                   \
    acc[0][0] = mfma32(a0h, b0l, acc[0][0]);                                   \
    acc[0][1] = mfma32(a0h, b1l, acc[0][1]);                                   \
    acc[1][0] = mfma32(a1h, b0l, acc[1][0]);                                   \
    acc[1][1] = mfma32(a1h, b1l, acc[1][1]);                                   \
    acc[0][0] = mfma32(a0l, b0h, acc[0][0]);                                   \
    acc[0][1] = mfma32(a0l, b1h, acc[0][1]);                                   \
    acc[1][0] = mfma32(a1l, b0h, acc[1][0]);                                   \
    acc[1][1] = mfma32(a1l, b1h, acc[1][1]);                                   \
    __builtin_amdgcn_s_setprio(0);                                             \
    bf16x8 a2h = *(const bf16x8*)&Ah[bufi][(wr<<7) + 64 + l31][co];            \
    bf16x8 a2l = *(const bf16x8*)&Al[bufi][(wr<<7) + 64 + l31][co];            \
    bf16x8 a3h = *(const bf16x8*)&Ah[bufi][(wr<<7) + 96 + l31][co];            \
    bf16x8 a3l = *(const bf16x8*)&Al[bufi][(wr<<7) + 96 + l31][co];            \
    __builtin_amdgcn_s_setprio(1);                                             \
    acc[2][0] = mfma32(a2h, b0h, acc[2][0]);                                   \
    acc[2][1] = mfma32(a2h, b1h, acc[2][1]);                                   \
    acc[3][0] = mfma32(a3h, b0h, acc[3][0]);                                   \
    acc[3][1] = mfma32(a3h, b1h, acc[3][1]);                                   \
    acc[2][0] = mfma32(a2h, b0l, acc[2][0]);                                   \
    acc[2][1] = mfma32(a2h, b1l, acc[2][1]);                                   \
    acc[3][0] = mfma32(a3h, b0l, acc[3][0]);                                   \
    acc[3][1] = mfma32(a3h, b1l, acc[3][1]);                                   \
    acc[2][0] = mfma32(a2l, b0h, acc[2][0]);                                   \
    acc[2][1] = mfma32(a2l, b1h, acc[2][1]);                                   \
    acc[3][0] = mfma32(a3l, b0h, acc[3][0]);                                   \
    acc[3][1] = mfma32(a3l, b1h, acc[3][1]);                                   \
    __builtin_amdgcn_s_setprio(0);                                             \
  } while(0)

  // prologue: stage tiles 0,1,2 (12 loads/wave in flight)
  STAGE(0, 0); STAGE(1, 16); STAGE(2, 32);

  // main loop: tiles 0..28, always 3 tiles ahead, counted vmcnt.
  // Order: drain-to-8 (tile tt landed) -> barrier (all waves done with
  // COMPUTE(tt-1) AND their tile-tt loads) -> stage tt+3 -> compute tt.
  for (int tt = 0; tt < 29; ++tt){
    WAITVM(8);
    __builtin_amdgcn_s_barrier();
    __builtin_amdgcn_sched_barrier(0);
    STAGE((tt+3)&3, (size_t)(tt+3)*16);
    COMPUTE(tt&3);
  }
  // tail: tiles 29,30,31 (no more staging; drain progressively)
  WAITVM(8);
  __builtin_amdgcn_s_barrier();
  __builtin_amdgcn_sched_barrier(0);
  COMPUTE(1);
  WAITVM(4);
  __builtin_amdgcn_s_barrier();
  __builtin_amdgcn_sched_barrier(0);
  COMPUTE(2);
  WAITVM(0);
  __builtin_amdgcn_s_barrier();
  __builtin_amdgcn_sched_barrier(0);
  COMPUTE(3);
#undef STAGE
#undef COMPUTE

  // epilogue (C/D layout verified in round 4)
  const size_t obase = (size_t)bz*((size_t)NN*MM);
#pragma unroll
  for (int m = 0; m < 4; ++m){
#pragma unroll
    for (int n = 0; n < 2; ++n){
      int col = bn*256 + (wc<<6) + (n<<5) + l31;
      float sv = svec[bz*MM + col];
#pragma unroll
      for (int g = 0; g < 16; ++g){
        int row = bm*256 + (wr<<7) + (m<<5) + (g&3) + ((g>>2)<<3) + ((lane>>5)<<2);
        O[obase + (size_t)row*MM + col] = conf[bz*NN + row] * (acc[m][n][g] + sv);
      }
    }
  }
}

// ---------------------------------------------------------------------------
// T x3 GEMM: T[row,col] = sum_k lidar[row,k]*At[col,k], hi/lo bf16 out.
// Block 128x128, 4 waves 2x2, wave 64x64 (4x4 frags).
// ---------------------------------------------------------------------------
__global__ __launch_bounds__(256) void gemm_T(
    const unsigned short* __restrict__ Ahg, const unsigned short* __restrict__ Alg,
    const unsigned short* __restrict__ Bhg, const unsigned short* __restrict__ Blg,
    unsigned short* __restrict__ O1, unsigned short* __restrict__ O2)
{
  __shared__ __attribute__((aligned(16))) unsigned short Ah[128][40];
  __shared__ __attribute__((aligned(16))) unsigned short Al[128][40];
  __shared__ __attribute__((aligned(16))) unsigned short Bh[128][40];
  __shared__ __attribute__((aligned(16))) unsigned short Bl[128][40];

  int bn, bm, bz; swz_xyz(bn, bm, bz);
  const int t = threadIdx.x;
  const int lane = t & 63, w = t >> 6;
  const int wrow = w >> 1, wcol = w & 1;
  const int lr = lane & 15, lk = (lane >> 4) << 3;

  f32x4 acc[4][4];
#pragma unroll
  for (int m = 0; m < 4; ++m)
#pragma unroll
    for (int n = 0; n < 4; ++n){ f32x4 z = {0.f,0.f,0.f,0.f}; acc[m][n] = z; }

  const size_t offA = (size_t)bz*((size_t)NN*DD) + ((size_t)bm*128)*DD;
  const size_t offB = ((size_t)bn*128)*DD;   // At shared across batches
  const unsigned short* Ahp = Ahg + offA;
  const unsigned short* Alp = Alg + offA;
  const unsigned short* Bhp = Bhg + offB;
  const unsigned short* Blp = Blg + offB;

  const int sr = t >> 2;
  const int sc = (t & 3) * 8;

  for (int k0 = 0; k0 < DD; k0 += 32){
    __syncthreads();
#pragma unroll
    for (int p = 0; p < 2; ++p){
      int r = sr + 64*p;
      *(u16x8*)&Ah[r][sc] = *(const u16x8*)(Ahp + (size_t)r*DD + k0 + sc);
      *(u16x8*)&Al[r][sc] = *(const u16x8*)(Alp + (size_t)r*DD + k0 + sc);
      *(u16x8*)&Bh[r][sc] = *(const u16x8*)(Bhp + (size_t)r*DD + k0 + sc);
      *(u16x8*)&Bl[r][sc] = *(const u16x8*)(Blp + (size_t)r*DD + k0 + sc);
    }
    __syncthreads();

    bf16x8 ah[4], al[4], bh[4], bl[4];
#pragma unroll
    for (int m = 0; m < 4; ++m){
      ah[m] = *(const bf16x8*)&Ah[wrow*64 + m*16 + lr][lk];
      al[m] = *(const bf16x8*)&Al[wrow*64 + m*16 + lr][lk];
    }
#pragma unroll
    for (int n = 0; n < 4; ++n){
      bh[n] = *(const bf16x8*)&Bh[wcol*64 + n*16 + lr][lk];
      bl[n] = *(const bf16x8*)&Bl[wcol*64 + n*16 + lr][lk];
    }
#pragma unroll
    for (int m = 0; m < 4; ++m)
#pragma unroll
      for (int n = 0; n < 4; ++n){
        acc[m][n] = mfma16(ah[m], bh[n], acc[m][n]);
        acc[m][n] = mfma16(ah[m], bl[n], acc[m][n]);
        acc[m][n] = mfma16(al[m], bh[n], acc[m][n]);
      }
  }

  const int orow = bm*128 + wrow*64;
  const int ocol = bn*128 + wcol*64;
#pragma unroll
  for (int m = 0; m < 4; ++m){
#pragma unroll
    for (int n = 0; n < 4; ++n){
      int col  = ocol + n*16 + lr;
      int row0 = orow + m*16 + ((lane >> 4) << 2);
#pragma unroll
      for (int r = 0; r < 4; ++r){
        int row = row0 + r;
        float v = acc[m][n][r];
        size_t idx = (size_t)bz*((size_t)NN*DD) + (size_t)row*DD + col;
        unsigned short h = f2bf(v);
        O1[idx] = h;
        O2[idx] = f2bf(v - bf2f(h));
      }
    }
  }
}

// ---------------------------------------------------------------------------
// Vt GEMM: Vt[e,m] = sum_k Wv[e,k]*cam[m,k] + bv[e], bf16 out.
// Block 128x128, 4 waves 2x2.
// ---------------------------------------------------------------------------
__global__ __launch_bounds__(256) void gemm_Vt(
    const unsigned short* __restrict__ Ag,   // wvH [D][D]
    const unsigned short* __restrict__ Bg,   // camHi [B,M,D]
    unsigned short* __restrict__ O,          // Vt [B,D,M]
    const float* __restrict__ bias)
{
  __shared__ __attribute__((aligned(16))) unsigned short Ah[128][40];
  __shared__ __attribute__((aligned(16))) unsigned short Bh[128][40];

  int bn, bm, bz; swz_xyz(bn, bm, bz);
  const int t = threadIdx.x;
  const int lane = t & 63, w = t >> 6;
  const int wrow = w >> 1, wcol = w & 1;
  const int lr = lane & 15, lk = (lane >> 4) << 3;

  f32x4 acc[4][4];
#pragma unroll
  for (int m = 0; m < 4; ++m)
#pragma unroll
    for (int n = 0; n < 4; ++n){ f32x4 z = {0.f,0.f,0.f,0.f}; acc[m][n] = z; }

  const unsigned short* Ap = Ag + ((size_t)bm*128)*DD;
  const unsigned short* Bp = Bg + (size_t)bz*((size_t)MM*DD) + ((size_t)bn*128)*DD;

  const int sr = t >> 2;
  const int sc = (t & 3) * 8;

  for (int k0 = 0; k0 < DD; k0 += 32){
    __syncthreads();
#pragma unroll
    for (int p = 0; p < 2; ++p){
      int r = sr + 64*p;
      *(u16x8*)&Ah[r][sc] = *(const u16x8*)(Ap + (size_t)r*DD + k0 + sc);
      *(u16x8*)&Bh[r][sc] = *(const u16x8*)(Bp + (size_t)r*DD + k0 + sc);
    }
    __syncthreads();

    bf16x8 af[4], bf[4];
#pragma unroll
    for (int m = 0; m < 4; ++m) af[m] = *(const bf16x8*)&Ah[wrow*64 + m*16 + lr][lk];
#pragma unroll
    for (int n = 0; n < 4; ++n) bf[n] = *(const bf16x8*)&Bh[wcol*64 + n*16 + lr][lk];
#pragma unroll
    for (int m = 0; m < 4; ++m)
#pragma unroll
      for (int n = 0; n < 4; ++n)
        acc[m][n] = mfma16(af[m], bf[n], acc[m][n]);
  }

  const int orow = bm*128 + wrow*64;   // e (V col)
  const int ocol = bn*128 + wcol*64;   // m (cam row)
#pragma unroll
  for (int m = 0; m < 4; ++m){
#pragma unroll
    for (int n = 0; n < 4; ++n){
      int col  = ocol + n*16 + lr;
      int row0 = orow + m*16 + ((lane >> 4) << 2);
#pragma unroll
      for (int r = 0; r < 4; ++r){
        int row = row0 + r;
        O[(size_t)bz*((size_t)DD*MM) + (size_t)row*MM + col] = f2bf(acc[m][n][r] + bias[row]);
      }
    }
  }
}

// ---------------------------------------------------------------------------
// PV GEMM: out[n,e] = sum_m P[n,m]*Vt[e,m].  Block 64(rows) x 256(cols),
// 4 waves 1x4, wave 64x64.  P bf16 at lda=2*MM (in-place in scores buffer).
// ---------------------------------------------------------------------------
__global__ __launch_bounds__(256) void gemm_pv(
    const unsigned short* __restrict__ P,
    const unsigned short* __restrict__ V,
    float* __restrict__ O)
{
  __shared__ __attribute__((aligned(16))) unsigned short Ah[64][40];
  __shared__ __attribute__((aligned(16))) unsigned short Bh[256][40];

  int bn, bm, bz; swz_xyz(bn, bm, bz);
  const int t = threadIdx.x;
  const int lane = t & 63, w = t >> 6;
  const int lr = lane & 15, lk = (lane >> 4) << 3;

  f32x4 acc[4][4];
#pragma unroll
  for (int m = 0; m < 4; ++m)
#pragma unroll
    for (int n = 0; n < 4; ++n){ f32x4 z = {0.f,0.f,0.f,0.f}; acc[m][n] = z; }

  const unsigned short* Ap = P + (size_t)bz*((size_t)NN*2*MM) + ((size_t)bm*64)*(2*MM);
  const unsigned short* Bp = V + (size_t)bz*((size_t)DD*MM) + ((size_t)bn*256)*MM;

  const int sr = t >> 2;          // 0..63
  const int sc = (t & 3) * 8;

  for (int k0 = 0; k0 < MM; k0 += 32){
    __syncthreads();
    *(u16x8*)&Ah[sr][sc] = *(const u16x8*)(Ap + (size_t)sr*(2*MM) + k0 + sc);
#pragma unroll
    for (int p = 0; p < 4; ++p){
      int r = sr + 64*p;
      *(u16x8*)&Bh[r][sc] = *(const u16x8*)(Bp + (size_t)r*MM + k0 + sc);
    }
    __syncthreads();

    bf16x8 af[4], bf[4];
#pragma unroll
    for (int m = 0; m < 4; ++m) af[m] = *(const bf16x8*)&Ah[m*16 + lr][lk];
#pragma unroll
    for (int n = 0; n < 4; ++n) bf[n] = *(const bf16x8*)&Bh[w*64 + n*16 + lr][lk];
#pragma unroll
    for (int m = 0; m < 4; ++m)
#pragma unroll
      for (int n = 0; n < 4; ++n)
        acc[m][n] = mfma16(af[m], bf[n], acc[m][n]);
  }

  const int orow0 = bm*64;
  const int ocol0 = bn*256 + w*64;
#pragma unroll
  for (int m = 0; m < 4; ++m){
#pragma unroll
    for (int n = 0; n < 4; ++n){
      int col  = ocol0 + n*16 + lr;
      int row0 = orow0 + m*16 + ((lane >> 4) << 2);
#pragma unroll
      for (int r = 0; r < 4; ++r){
        int row = row0 + r;
        O[(size_t)bz*((size_t)NN*DD) + (size_t)row*DD + col] = acc[m][n][r];
      }
    }
  }
}

// ---------------------------------------------------------------------------
// Row softmax over M=2048, f32 in, bf16 out in-place (row's first 4KB)
// ---------------------------------------------------------------------------
__global__ __launch_bounds__(256) void softmax_kernel(float* __restrict__ scores){
  const size_t row = blockIdx.x;
  float* src = scores + row * MM;
  unsigned short* dst = (unsigned short*)scores + row * (size_t)(2*MM);
  const int t = threadIdx.x;

  float4 v0 = ((const float4*)src)[t];
  float4 v1 = ((const float4*)src)[t + 256];

  float mx = fmaxf(fmaxf(fmaxf(v0.x,v0.y), fmaxf(v0.z,v0.w)),
                   fmaxf(fmaxf(v1.x,v1.y), fmaxf(v1.z,v1.w)));
  for (int o = 32; o; o >>= 1) mx = fmaxf(mx, __shfl_xor(mx, o));
  __shared__ float red[4];
  if ((t & 63) == 0) red[t >> 6] = mx;
  __syncthreads();
  mx = fmaxf(fmaxf(red[0], red[1]), fmaxf(red[2], red[3]));

  float e0x = __expf(v0.x - mx), e0y = __expf(v0.y - mx);
  float e0z = __expf(v0.z - mx), e0w = __expf(v0.w - mx);
  float e1x = __expf(v1.x - mx), e1y = __expf(v1.y - mx);
  float e1z = __expf(v1.z - mx), e1w = __expf(v1.w - mx);
  float s = e0x+e0y+e0z+e0w+e1x+e1y+e1z+e1w;
  for (int o = 32; o; o >>= 1) s += __shfl_xor(s, o);
  __syncthreads();
  if ((t & 63) == 0) red[t >> 6] = s;
  __syncthreads();
  float inv = 1.f / (red[0] + red[1] + red[2] + red[3]);

  ushort4 p0; p0.x=f2bf(e0x*inv); p0.y=f2bf(e0y*inv); p0.z=f2bf(e0z*inv); p0.w=f2bf(e0w*inv);
  ushort4 p1; p1.x=f2bf(e1x*inv); p1.y=f2bf(e1y*inv); p1.z=f2bf(e1z*inv); p1.w=f2bf(e1w*inv);
  ((ushort4*)dst)[t]       = p0;
  ((ushort4*)dst)[t + 256] = p1;
}

// ---------------------------------------------------------------------------
extern "C" void kernel_launch(void* const* d_in, const int* in_sizes, int n_in,
                              void* d_out, int out_size, void* d_ws, size_t ws_size,
                              hipStream_t stream) {
  const float* lidar  = (const float*)d_in[0];   // [B,N,D]
  const float* camera = (const float*)d_in[1];   // [B,M,D]
  const float* lconf  = (const float*)d_in[2];   // [B,N,1]
  // d_in[3] camera_confidence: unused by the reference
  const float* Wq = (const float*)d_in[4];
  const float* bq = (const float*)d_in[5];
  const float* Wk = (const float*)d_in[6];
  // d_in[7] bk: row-constant in scores -> softmax-invariant, dropped
  const float* Wv = (const float*)d_in[8];
  const float* bv = (const float*)d_in[9];
  float* out = (float*)d_out;                    // [B,N,D] f32

  // workspace layout (bytes), total ~218 MB
  char* ws = (char*)d_ws;
  float*          scores = (float*)(ws + 0);                  // [B,N,M] f32 134.2MB (P bf16 in-place)
  // transient aliases inside scores region (dead before scores is written):
  unsigned short* liHi   = (unsigned short*)(ws + 0);         // [B,N,D] 16.8MB
  unsigned short* liLo   = (unsigned short*)(ws + 16777216);  // [B,N,D] 16.8MB
  unsigned short* atHi   = (unsigned short*)(ws + 33554432);  // [D,D]   0.5MB
  unsigned short* atLo   = (unsigned short*)(ws + 34078720);  // [D,D]   0.5MB
  float*          c2     = (float*)(ws + 34603008);           // [D]
  unsigned short* wvH    = (unsigned short*)(ws + 34605056);  // [D,D]   0.5MB
  // persistent:
  unsigned short* Thi    = (unsigned short*)(ws + 134217728); // [B,N,D] 16.8MB
  unsigned short* Tlo    = (unsigned short*)(ws + 150994944); // [B,N,D] 16.8MB
  unsigned short* camHi  = (unsigned short*)(ws + 167772160); // [B,M,D] 16.8MB
  unsigned short* camLo  = (unsigned short*)(ws + 184549376); // [B,M,D] 16.8MB
  unsigned short* Vt     = (unsigned short*)(ws + 201326592); // [B,D,M] 16.8MB
  float*          svec   = (float*)(ws + 218103808);          // [B,M]

  // pre-splits
  split2_kernel<<<dim3(2048), 256, 0, stream>>>(camera, camHi, camLo, BB*MM*DD/4);
  split2_kernel<<<dim3(2048), 256, 0, stream>>>(lidar,  liHi,  liLo,  BB*NN*DD/4);
  split2_kernel<<<dim3(512),  256, 0, stream>>>(Wv,     wvH,   nullptr, DD*DD/4);
  at_kernel<<<dim3(16,16), 256, 0, stream>>>(Wq, Wk, atHi, atLo);
  c2_kernel<<<dim3(2), 256, 0, stream>>>(bq, Wk, c2);
  s_kernel<<<dim3(BB*MM), 64, 0, stream>>>(camera, c2, svec);

  // T = lidar @ At^T (x3) -> Thi/Tlo
  gemm_T<<<dim3(DD/128, NN/128, BB), 256, 0, stream>>>(
      liHi, liLo, atHi, atLo, Thi, Tlo);

  // Vt[e,m] = Wv[e,:].cam[m,:] + bv[e]
  gemm_Vt<<<dim3(MM/128, DD/128, BB), 256, 0, stream>>>(
      wvH, camHi, Vt, bv);

  // scores = conf * (T @ cam^T + svec)  (x3, 3-deep pipelined, 32x32 MFMA)
  gemm_scores<<<dim3(MM/256, NN/256, BB), 512, 0, stream>>>(
      Thi, Tlo, camHi, camLo, scores, lconf, svec);

  // row softmax, P bf16 in-place
  softmax_kernel<<<dim3(BB*NN), 256, 0, stream>>>(scores);

  // out = P @ Vt^T
  gemm_pv<<<dim3(DD/256, NN/64, BB), 256, 0, stream>>>(
      (const unsigned short*)scores, Vt, out);
}

// Round 7
// 278.880 us; speedup vs baseline: 1.2355x; 1.2355x over previous
//
#include <hip/hip_runtime.h>
#include <hip/hip_bf16.h>

#define BB 8
#define NN 2048
#define MM 2048
#define DD 512

typedef __attribute__((ext_vector_type(8))) _Float16 f16x8;
typedef __attribute__((ext_vector_type(4))) float f32x4;
typedef __attribute__((ext_vector_type(8))) unsigned short u16x8;

__device__ __forceinline__ unsigned short f2h(float x){
  union { _Float16 h; unsigned short u; } cv;
  cv.h = (_Float16)x;           // v_cvt_f16_f32, RTN-even
  return cv.u;
}
__device__ __forceinline__ f32x4 mfmah(f16x8 a, f16x8 b, f32x4 c){
  return __builtin_amdgcn_mfma_f32_16x16x32_f16(a, b, c, 0, 0, 0);
}

// batch->XCD swizzle: flat id f -> bz = f&7 (XCD presumed f%8), bijective
// (requires gridDim.z == 8)
__device__ __forceinline__ void swz_xyz(int& bn, int& bm, int& bz){
  int f = ((int)blockIdx.z * (int)gridDim.y + (int)blockIdx.y) * (int)gridDim.x
        + (int)blockIdx.x;
  bz = f & 7;
  int r = f >> 3;
  bn = r % (int)gridDim.x;
  bm = r / (int)gridDim.x;
}

// ---------------------------------------------------------------------------
// cvt16: f32 -> f16, float4-vectorized, grid-stride
// ---------------------------------------------------------------------------
__global__ __launch_bounds__(256) void cvt16_kernel(const float* __restrict__ in,
    unsigned short* __restrict__ out, int n4){
  int i = blockIdx.x*256 + threadIdx.x;
  const int stride = gridDim.x*256;
  for (; i < n4; i += stride){
    float4 v = ((const float4*)in)[i];
    ushort4 h; h.x=f2h(v.x); h.y=f2h(v.y); h.z=f2h(v.z); h.w=f2h(v.w);
    ((ushort4*)out)[i] = h;
  }
}

// ---------------------------------------------------------------------------
// K0: At[j][i] = sum_e Wq[e][i] * Wk[e][j], f32 accum, f16 out
// ---------------------------------------------------------------------------
__global__ __launch_bounds__(256) void at_kernel(const float* __restrict__ Wq,
                                                 const float* __restrict__ Wk,
                                                 unsigned short* __restrict__ atH){
  const int i0 = blockIdx.x * 32, j0 = blockIdx.y * 32;
  __shared__ float q_s[32][33];
  __shared__ float k_s[32][33];
  const int t = threadIdx.x;
  const int tx = t & 15, ty = t >> 4;
  float acc[2][2] = {{0.f,0.f},{0.f,0.f}};
  for (int e0 = 0; e0 < DD; e0 += 32){
    __syncthreads();
#pragma unroll
    for (int p = 0; p < 4; ++p){
      int idx = t + 256*p;
      int e = idx >> 5, c = idx & 31;
      q_s[e][c] = Wq[(size_t)(e0+e)*DD + i0 + c];
      k_s[e][c] = Wk[(size_t)(e0+e)*DD + j0 + c];
    }
    __syncthreads();
#pragma unroll 8
    for (int e = 0; e < 32; ++e){
      float q0 = q_s[e][2*tx], q1 = q_s[e][2*tx+1];
      float k0 = k_s[e][2*ty], k1 = k_s[e][2*ty+1];
      acc[0][0] += k0*q0; acc[0][1] += k0*q1;
      acc[1][0] += k1*q0; acc[1][1] += k1*q1;
    }
  }
#pragma unroll
  for (int a = 0; a < 2; ++a)
#pragma unroll
    for (int b = 0; b < 2; ++b)
      atH[(size_t)(j0 + 2*ty + a)*DD + i0 + 2*tx + b] = f2h(acc[a][b]);
}

// c2[d] = sum_e bq[e] * Wk[e][d]
__global__ __launch_bounds__(256) void c2_kernel(const float* __restrict__ bq,
                                                 const float* __restrict__ Wk,
                                                 float* __restrict__ c2){
  int d = blockIdx.x * 256 + threadIdx.x;
  float a = 0.f;
  for (int e = 0; e < DD; ++e) a += bq[e] * Wk[(size_t)e*DD + d];
  c2[d] = a;
}

// s[b*M+m] = dot(camera[b,m,:], c2)
__global__ __launch_bounds__(64) void s_kernel(const float* __restrict__ cam,
                                               const float* __restrict__ c2,
                                               float* __restrict__ svec){
  size_t row = blockIdx.x;
  const float* y = cam + row * DD;
  int l = threadIdx.x;
  float a = 0.f;
#pragma unroll
  for (int i = 0; i < 8; ++i) a += y[l + 64*i] * c2[l + 64*i];
  for (int o = 32; o; o >>= 1) a += __shfl_xor(a, o);
  if (l == 0) svec[row] = a;
}

// ---------------------------------------------------------------------------
// Plain f16 GEMM, BT form: O[row,col] = sum_k A[row,k]*B[col,k], f16 out.
// Block 128x128, 4 waves 2x2, wave 64x64 (4x4 frags of 16x16x32 f16).
// MODE 0: plain.  MODE 1: + bias[row].
// ---------------------------------------------------------------------------
template<int MODE>
__global__ __launch_bounds__(256) void gemm_h128(
    const unsigned short* __restrict__ Ag, long sA, int lda,
    const unsigned short* __restrict__ Bg, long sB, int ldb,
    unsigned short* __restrict__ O, long sO, int ldo,
    const float* __restrict__ bias)
{
  __shared__ __attribute__((aligned(16))) unsigned short Ah[128][40];
  __shared__ __attribute__((aligned(16))) unsigned short Bh[128][40];

  int bn, bm, bz; swz_xyz(bn, bm, bz);
  const int t = threadIdx.x;
  const int lane = t & 63, w = t >> 6;
  const int wrow = w >> 1, wcol = w & 1;
  const int lr = lane & 15, lk = (lane >> 4) << 3;

  f32x4 acc[4][4];
#pragma unroll
  for (int m = 0; m < 4; ++m)
#pragma unroll
    for (int n = 0; n < 4; ++n){ f32x4 z = {0.f,0.f,0.f,0.f}; acc[m][n] = z; }

  const unsigned short* Ap = Ag + (size_t)bz*(size_t)sA + ((size_t)bm*128)*(size_t)lda;
  const unsigned short* Bp = Bg + (size_t)bz*(size_t)sB + ((size_t)bn*128)*(size_t)ldb;

  const int sr = t >> 2;          // 0..63
  const int sc = (t & 3) * 8;

  for (int k0 = 0; k0 < DD; k0 += 32){
    __syncthreads();
#pragma unroll
    for (int p = 0; p < 2; ++p){
      int r = sr + 64*p;
      *(u16x8*)&Ah[r][sc] = *(const u16x8*)(Ap + (size_t)r*lda + k0 + sc);
      *(u16x8*)&Bh[r][sc] = *(const u16x8*)(Bp + (size_t)r*ldb + k0 + sc);
    }
    __syncthreads();

    f16x8 af[4], bf[4];
#pragma unroll
    for (int m = 0; m < 4; ++m) af[m] = *(const f16x8*)&Ah[wrow*64 + m*16 + lr][lk];
#pragma unroll
    for (int n = 0; n < 4; ++n) bf[n] = *(const f16x8*)&Bh[wcol*64 + n*16 + lr][lk];
#pragma unroll
    for (int m = 0; m < 4; ++m)
#pragma unroll
      for (int n = 0; n < 4; ++n)
        acc[m][n] = mfmah(af[m], bf[n], acc[m][n]);
  }

  const int orow = bm*128 + wrow*64;
  const int ocol = bn*128 + wcol*64;
#pragma unroll
  for (int m = 0; m < 4; ++m){
#pragma unroll
    for (int n = 0; n < 4; ++n){
      int col  = ocol + n*16 + lr;
      int row0 = orow + m*16 + ((lane >> 4) << 2);
#pragma unroll
      for (int r = 0; r < 4; ++r){
        int row = row0 + r;
        float v = acc[m][n][r];
        if constexpr (MODE == 1) v += bias[row];
        O[(size_t)bz*(size_t)sO + (size_t)row*ldo + col] = f2h(v);
      }
    }
  }
}

// ---------------------------------------------------------------------------
// scores f16 GEMM: O[row,col] = conf[row]*(sum_k T[row,k]*cam[col,k]+svec[col])
// Block 128(rows) x 256(cols), 4 waves, wave tile 128x64 (8x4 frags).
// ---------------------------------------------------------------------------
__global__ __launch_bounds__(256) void gemm_scores(
    const unsigned short* __restrict__ Th, const unsigned short* __restrict__ camH,
    float* __restrict__ O,
    const float* __restrict__ conf, const float* __restrict__ svec)
{
  __shared__ __attribute__((aligned(16))) unsigned short Ah[128][40];
  __shared__ __attribute__((aligned(16))) unsigned short Bh[256][40];

  int bn, bm, bz; swz_xyz(bn, bm, bz);   // grid (8,16,8)
  const int t = threadIdx.x;
  const int lane = t & 63, w = t >> 6;
  const int lr = lane & 15, lk = (lane >> 4) << 3;

  f32x4 acc[8][4];
#pragma unroll
  for (int m = 0; m < 8; ++m)
#pragma unroll
    for (int n = 0; n < 4; ++n){ f32x4 z = {0.f,0.f,0.f,0.f}; acc[m][n] = z; }

  const unsigned short* Ap = Th   + (size_t)bz*((size_t)NN*DD) + ((size_t)bm*128)*DD;
  const unsigned short* Bp = camH + (size_t)bz*((size_t)MM*DD) + ((size_t)bn*256)*DD;

  const int sr = t >> 2;          // 0..63
  const int sc = (t & 3) * 8;     // 0,8,16,24

  for (int k0 = 0; k0 < DD; k0 += 32){
    __syncthreads();
#pragma unroll
    for (int p = 0; p < 2; ++p){
      int r = sr + 64*p;
      *(u16x8*)&Ah[r][sc] = *(const u16x8*)(Ap + (size_t)r*DD + k0 + sc);
    }
#pragma unroll
    for (int p = 0; p < 4; ++p){
      int r = sr + 64*p;
      *(u16x8*)&Bh[r][sc] = *(const u16x8*)(Bp + (size_t)r*DD + k0 + sc);
    }
    __syncthreads();

    f16x8 bhf[4];
#pragma unroll
    for (int n = 0; n < 4; ++n)
      bhf[n] = *(const f16x8*)&Bh[w*64 + n*16 + lr][lk];
#pragma unroll
    for (int m = 0; m < 8; ++m){
      f16x8 ahf = *(const f16x8*)&Ah[m*16 + lr][lk];
#pragma unroll
      for (int n = 0; n < 4; ++n)
        acc[m][n] = mfmah(ahf, bhf[n], acc[m][n]);
    }
  }

  const int ocol0 = bn*256 + w*64;
  const int orow0 = bm*128;
  const size_t obase = (size_t)bz*((size_t)NN*MM);
#pragma unroll
  for (int m = 0; m < 8; ++m){
#pragma unroll
    for (int n = 0; n < 4; ++n){
      int col  = ocol0 + n*16 + lr;
      float sv = svec[bz*MM + col];
      int row0 = orow0 + m*16 + ((lane >> 4) << 2);
#pragma unroll
      for (int r = 0; r < 4; ++r){
        int row = row0 + r;
        O[obase + (size_t)row*MM + col]
            = conf[bz*NN + row] * (acc[m][n][r] + sv);
      }
    }
  }
}

// ---------------------------------------------------------------------------
// PV GEMM: out[n,e] = sum_m P[n,m]*Vt[e,m].  Block 64(rows) x 256(cols),
// 4 waves 1x4, wave 64x64.  P f16 at lda=2*MM (in-place in scores buffer).
// ---------------------------------------------------------------------------
__global__ __launch_bounds__(256) void gemm_pv(
    const unsigned short* __restrict__ P,
    const unsigned short* __restrict__ V,
    float* __restrict__ O)
{
  __shared__ __attribute__((aligned(16))) unsigned short Ah[64][40];
  __shared__ __attribute__((aligned(16))) unsigned short Bh[256][40];

  int bn, bm, bz; swz_xyz(bn, bm, bz);
  const int t = threadIdx.x;
  const int lane = t & 63, w = t >> 6;
  const int lr = lane & 15, lk = (lane >> 4) << 3;

  f32x4 acc[4][4];
#pragma unroll
  for (int m = 0; m < 4; ++m)
#pragma unroll
    for (int n = 0; n < 4; ++n){ f32x4 z = {0.f,0.f,0.f,0.f}; acc[m][n] = z; }

  const unsigned short* Ap = P + (size_t)bz*((size_t)NN*2*MM) + ((size_t)bm*64)*(2*MM);
  const unsigned short* Bp = V + (size_t)bz*((size_t)DD*MM) + ((size_t)bn*256)*MM;

  const int sr = t >> 2;          // 0..63
  const int sc = (t & 3) * 8;

  for (int k0 = 0; k0 < MM; k0 += 32){
    __syncthreads();
    *(u16x8*)&Ah[sr][sc] = *(const u16x8*)(Ap + (size_t)sr*(2*MM) + k0 + sc);
#pragma unroll
    for (int p = 0; p < 4; ++p){
      int r = sr + 64*p;
      *(u16x8*)&Bh[r][sc] = *(const u16x8*)(Bp + (size_t)r*MM + k0 + sc);
    }
    __syncthreads();

    f16x8 af[4], bf[4];
#pragma unroll
    for (int m = 0; m < 4; ++m) af[m] = *(const f16x8*)&Ah[m*16 + lr][lk];
#pragma unroll
    for (int n = 0; n < 4; ++n) bf[n] = *(const f16x8*)&Bh[w*64 + n*16 + lr][lk];
#pragma unroll
    for (int m = 0; m < 4; ++m)
#pragma unroll
      for (int n = 0; n < 4; ++n)
        acc[m][n] = mfmah(af[m], bf[n], acc[m][n]);
  }

  const int orow0 = bm*64;
  const int ocol0 = bn*256 + w*64;
#pragma unroll
  for (int m = 0; m < 4; ++m){
#pragma unroll
    for (int n = 0; n < 4; ++n){
      int col  = ocol0 + n*16 + lr;
      int row0 = orow0 + m*16 + ((lane >> 4) << 2);
#pragma unroll
      for (int r = 0; r < 4; ++r){
        int row = row0 + r;
        O[(size_t)bz*((size_t)NN*DD) + (size_t)row*DD + col] = acc[m][n][r];
      }
    }
  }
}

// ---------------------------------------------------------------------------
// Row softmax over M=2048, f32 in, f16 out in-place (row's first 4KB)
// ---------------------------------------------------------------------------
__global__ __launch_bounds__(256) void softmax_kernel(float* __restrict__ scores){
  const size_t row = blockIdx.x;
  float* src = scores + row * MM;
  unsigned short* dst = (unsigned short*)scores + row * (size_t)(2*MM);
  const int t = threadIdx.x;

  float4 v0 = ((const float4*)src)[t];
  float4 v1 = ((const float4*)src)[t + 256];

  float mx = fmaxf(fmaxf(fmaxf(v0.x,v0.y), fmaxf(v0.z,v0.w)),
                   fmaxf(fmaxf(v1.x,v1.y), fmaxf(v1.z,v1.w)));
  for (int o = 32; o; o >>= 1) mx = fmaxf(mx, __shfl_xor(mx, o));
  __shared__ float red[4];
  if ((t & 63) == 0) red[t >> 6] = mx;
  __syncthreads();
  mx = fmaxf(fmaxf(red[0], red[1]), fmaxf(red[2], red[3]));

  float e0x = __expf(v0.x - mx), e0y = __expf(v0.y - mx);
  float e0z = __expf(v0.z - mx), e0w = __expf(v0.w - mx);
  float e1x = __expf(v1.x - mx), e1y = __expf(v1.y - mx);
  float e1z = __expf(v1.z - mx), e1w = __expf(v1.w - mx);
  float s = e0x+e0y+e0z+e0w+e1x+e1y+e1z+e1w;
  for (int o = 32; o; o >>= 1) s += __shfl_xor(s, o);
  __syncthreads();
  if ((t & 63) == 0) red[t >> 6] = s;
  __syncthreads();
  float inv = 1.f / (red[0] + red[1] + red[2] + red[3]);

  ushort4 p0; p0.x=f2h(e0x*inv); p0.y=f2h(e0y*inv); p0.z=f2h(e0z*inv); p0.w=f2h(e0w*inv);
  ushort4 p1; p1.x=f2h(e1x*inv); p1.y=f2h(e1y*inv); p1.z=f2h(e1z*inv); p1.w=f2h(e1w*inv);
  ((ushort4*)dst)[t]       = p0;
  ((ushort4*)dst)[t + 256] = p1;
}

// ---------------------------------------------------------------------------
extern "C" void kernel_launch(void* const* d_in, const int* in_sizes, int n_in,
                              void* d_out, int out_size, void* d_ws, size_t ws_size,
                              hipStream_t stream) {
  const float* lidar  = (const float*)d_in[0];   // [B,N,D]
  const float* camera = (const float*)d_in[1];   // [B,M,D]
  const float* lconf  = (const float*)d_in[2];   // [B,N,1]
  // d_in[3] camera_confidence: unused by the reference
  const float* Wq = (const float*)d_in[4];
  const float* bq = (const float*)d_in[5];
  const float* Wk = (const float*)d_in[6];
  // d_in[7] bk: row-constant in scores -> softmax-invariant, dropped
  const float* Wv = (const float*)d_in[8];
  const float* bv = (const float*)d_in[9];
  float* out = (float*)d_out;                    // [B,N,D] f32

  // workspace layout (bytes), total ~185 MB
  char* ws = (char*)d_ws;
  float*          scores = (float*)(ws + 0);                  // [B,N,M] f32 134.2MB (P f16 in-place)
  // transient aliases inside scores region (dead before scores is written):
  unsigned short* liH    = (unsigned short*)(ws + 0);         // [B,N,D] f16 16.8MB
  unsigned short* atH    = (unsigned short*)(ws + 16777216);  // [D,D]   f16 0.5MB
  unsigned short* wvH    = (unsigned short*)(ws + 17301504);  // [D,D]   f16 0.5MB
  float*          c2     = (float*)(ws + 17825792);           // [D]
  // persistent:
  unsigned short* Th     = (unsigned short*)(ws + 134217728); // [B,N,D] f16 16.8MB
  unsigned short* camH   = (unsigned short*)(ws + 150994944); // [B,M,D] f16 16.8MB
  unsigned short* Vt     = (unsigned short*)(ws + 167772160); // [B,D,M] f16 16.8MB
  float*          svec   = (float*)(ws + 184549376);          // [B,M]

  // f32 -> f16 conversions
  cvt16_kernel<<<dim3(2048), 256, 0, stream>>>(camera, camH, BB*MM*DD/4);
  cvt16_kernel<<<dim3(2048), 256, 0, stream>>>(lidar,  liH,  BB*NN*DD/4);
  cvt16_kernel<<<dim3(256),  256, 0, stream>>>(Wv,     wvH,  DD*DD/4);
  at_kernel<<<dim3(16,16), 256, 0, stream>>>(Wq, Wk, atH);
  c2_kernel<<<dim3(2), 256, 0, stream>>>(bq, Wk, c2);
  s_kernel<<<dim3(BB*MM), 64, 0, stream>>>(camera, c2, svec);

  // T = lidar @ At^T  (f16) -> Th
  gemm_h128<0><<<dim3(DD/128, NN/128, BB), 256, 0, stream>>>(
      liH, (long)NN*DD, DD,  atH, 0, DD,
      Th, (long)NN*DD, DD, nullptr);

  // Vt[e,m] = Wv[e,:].cam[m,:] + bv[e]  (f16)
  gemm_h128<1><<<dim3(MM/128, DD/128, BB), 256, 0, stream>>>(
      wvH, 0, DD,  camH, (long)MM*DD, DD,
      Vt, (long)DD*MM, MM, bv);

  // scores = conf * (T @ cam^T + svec)  (f16 inputs, f32 out)
  gemm_scores<<<dim3(MM/256, NN/128, BB), 256, 0, stream>>>(
      Th, camH, scores, lconf, svec);

  // row softmax, P f16 in-place
  softmax_kernel<<<dim3(BB*NN), 256, 0, stream>>>(scores);

  // out = P @ Vt^T  (f16)
  gemm_pv<<<dim3(DD/256, NN/64, BB), 256, 0, stream>>>(
      (const unsigned short*)scores, Vt, out);
}

// Round 8
// 248.781 us; speedup vs baseline: 1.3850x; 1.1210x over previous
//
#include <hip/hip_runtime.h>
#include <hip/hip_bf16.h>

#define BB 8
#define NN 2048
#define MM 2048
#define DD 512

typedef __attribute__((ext_vector_type(8))) _Float16 f16x8;
typedef __attribute__((ext_vector_type(4))) float f32x4;
typedef __attribute__((ext_vector_type(8))) unsigned short u16x8;

__device__ __forceinline__ unsigned short f2h(float x){
  union { _Float16 h; unsigned short u; } cv;
  cv.h = (_Float16)x;           // v_cvt_f16_f32, RTN-even
  return cv.u;
}
__device__ __forceinline__ f32x4 mfmah(f16x8 a, f16x8 b, f32x4 c){
  return __builtin_amdgcn_mfma_f32_16x16x32_f16(a, b, c, 0, 0, 0);
}

// batch->XCD swizzle: flat id f -> bz = f&7 (XCD presumed f%8), bijective
// (requires gridDim.z == 8)
__device__ __forceinline__ void swz_xyz(int& bn, int& bm, int& bz){
  int f = ((int)blockIdx.z * (int)gridDim.y + (int)blockIdx.y) * (int)gridDim.x
        + (int)blockIdx.x;
  bz = f & 7;
  int r = f >> 3;
  bn = r % (int)gridDim.x;
  bm = r / (int)gridDim.x;
}

// ---------------------------------------------------------------------------
// cvt16: f32 -> f16, float4-vectorized, grid-stride
// ---------------------------------------------------------------------------
__global__ __launch_bounds__(256) void cvt16_kernel(const float* __restrict__ in,
    unsigned short* __restrict__ out, int n4){
  int i = blockIdx.x*256 + threadIdx.x;
  const int stride = gridDim.x*256;
  for (; i < n4; i += stride){
    float4 v = ((const float4*)in)[i];
    ushort4 h; h.x=f2h(v.x); h.y=f2h(v.y); h.z=f2h(v.z); h.w=f2h(v.w);
    ((ushort4*)out)[i] = h;
  }
}

// ---------------------------------------------------------------------------
// K0: At[j][i] = sum_e Wq[e][i] * Wk[e][j], f32 accum, f16 out
// ---------------------------------------------------------------------------
__global__ __launch_bounds__(256) void at_kernel(const float* __restrict__ Wq,
                                                 const float* __restrict__ Wk,
                                                 unsigned short* __restrict__ atH){
  const int i0 = blockIdx.x * 32, j0 = blockIdx.y * 32;
  __shared__ float q_s[32][33];
  __shared__ float k_s[32][33];
  const int t = threadIdx.x;
  const int tx = t & 15, ty = t >> 4;
  float acc[2][2] = {{0.f,0.f},{0.f,0.f}};
  for (int e0 = 0; e0 < DD; e0 += 32){
    __syncthreads();
#pragma unroll
    for (int p = 0; p < 4; ++p){
      int idx = t + 256*p;
      int e = idx >> 5, c = idx & 31;
      q_s[e][c] = Wq[(size_t)(e0+e)*DD + i0 + c];
      k_s[e][c] = Wk[(size_t)(e0+e)*DD + j0 + c];
    }
    __syncthreads();
#pragma unroll 8
    for (int e = 0; e < 32; ++e){
      float q0 = q_s[e][2*tx], q1 = q_s[e][2*tx+1];
      float k0 = k_s[e][2*ty], k1 = k_s[e][2*ty+1];
      acc[0][0] += k0*q0; acc[0][1] += k0*q1;
      acc[1][0] += k1*q0; acc[1][1] += k1*q1;
    }
  }
#pragma unroll
  for (int a = 0; a < 2; ++a)
#pragma unroll
    for (int b = 0; b < 2; ++b)
      atH[(size_t)(j0 + 2*ty + a)*DD + i0 + 2*tx + b] = f2h(acc[a][b]);
}

// c2[d] = sum_e bq[e] * Wk[e][d]
__global__ __launch_bounds__(256) void c2_kernel(const float* __restrict__ bq,
                                                 const float* __restrict__ Wk,
                                                 float* __restrict__ c2){
  int d = blockIdx.x * 256 + threadIdx.x;
  float a = 0.f;
  for (int e = 0; e < DD; ++e) a += bq[e] * Wk[(size_t)e*DD + d];
  c2[d] = a;
}

// s[b*M+m] = dot(camera[b,m,:], c2)
__global__ __launch_bounds__(64) void s_kernel(const float* __restrict__ cam,
                                               const float* __restrict__ c2,
                                               float* __restrict__ svec){
  size_t row = blockIdx.x;
  const float* y = cam + row * DD;
  int l = threadIdx.x;
  float a = 0.f;
#pragma unroll
  for (int i = 0; i < 8; ++i) a += y[l + 64*i] * c2[l + 64*i];
  for (int o = 32; o; o >>= 1) a += __shfl_xor(a, o);
  if (l == 0) svec[row] = a;
}

// ---------------------------------------------------------------------------
// Plain f16 GEMM, BT form: O[row,col] = sum_k A[row,k]*B[col,k], f16 out.
// Block 128x128, 4 waves 2x2, wave 64x64 (4x4 frags of 16x16x32 f16).
// MODE 0: plain.  MODE 1: + bias[row].
// ---------------------------------------------------------------------------
template<int MODE>
__global__ __launch_bounds__(256) void gemm_h128(
    const unsigned short* __restrict__ Ag, long sA, int lda,
    const unsigned short* __restrict__ Bg, long sB, int ldb,
    unsigned short* __restrict__ O, long sO, int ldo,
    const float* __restrict__ bias)
{
  __shared__ __attribute__((aligned(16))) unsigned short Ah[128][40];
  __shared__ __attribute__((aligned(16))) unsigned short Bh[128][40];

  int bn, bm, bz; swz_xyz(bn, bm, bz);
  const int t = threadIdx.x;
  const int lane = t & 63, w = t >> 6;
  const int wrow = w >> 1, wcol = w & 1;
  const int lr = lane & 15, lk = (lane >> 4) << 3;

  f32x4 acc[4][4];
#pragma unroll
  for (int m = 0; m < 4; ++m)
#pragma unroll
    for (int n = 0; n < 4; ++n){ f32x4 z = {0.f,0.f,0.f,0.f}; acc[m][n] = z; }

  const unsigned short* Ap = Ag + (size_t)bz*(size_t)sA + ((size_t)bm*128)*(size_t)lda;
  const unsigned short* Bp = Bg + (size_t)bz*(size_t)sB + ((size_t)bn*128)*(size_t)ldb;

  const int sr = t >> 2;          // 0..63
  const int sc = (t & 3) * 8;

  for (int k0 = 0; k0 < DD; k0 += 32){
    __syncthreads();
#pragma unroll
    for (int p = 0; p < 2; ++p){
      int r = sr + 64*p;
      *(u16x8*)&Ah[r][sc] = *(const u16x8*)(Ap + (size_t)r*lda + k0 + sc);
      *(u16x8*)&Bh[r][sc] = *(const u16x8*)(Bp + (size_t)r*ldb + k0 + sc);
    }
    __syncthreads();

    f16x8 af[4], bf[4];
#pragma unroll
    for (int m = 0; m < 4; ++m) af[m] = *(const f16x8*)&Ah[wrow*64 + m*16 + lr][lk];
#pragma unroll
    for (int n = 0; n < 4; ++n) bf[n] = *(const f16x8*)&Bh[wcol*64 + n*16 + lr][lk];
#pragma unroll
    for (int m = 0; m < 4; ++m)
#pragma unroll
      for (int n = 0; n < 4; ++n)
        acc[m][n] = mfmah(af[m], bf[n], acc[m][n]);
  }

  const int orow = bm*128 + wrow*64;
  const int ocol = bn*128 + wcol*64;
#pragma unroll
  for (int m = 0; m < 4; ++m){
#pragma unroll
    for (int n = 0; n < 4; ++n){
      int col  = ocol + n*16 + lr;
      int row0 = orow + m*16 + ((lane >> 4) << 2);
#pragma unroll
      for (int r = 0; r < 4; ++r){
        int row = row0 + r;
        float v = acc[m][n][r];
        if constexpr (MODE == 1) v += bias[row];
        O[(size_t)bz*(size_t)sO + (size_t)row*ldo + col] = f2h(v);
      }
    }
  }
}

// ---------------------------------------------------------------------------
// scores f16 GEMM: O[row,col] = conf[row]*(sum_k T[row,k]*cam[col,k]+svec[col])
// Block 128(rows) x 256(cols), 8 waves (2 row x 4 col), wave tile 64x64
// (4x4 frags of 16x16x32) -> acc 64 VGPR, stays under the 128-VGPR
// occupancy cliff (R7 post-mortem: 8x4 acc -> 168 VGPR -> 2 waves/SIMD).
// ---------------------------------------------------------------------------
__global__ __launch_bounds__(512) void gemm_scores(
    const unsigned short* __restrict__ Th, const unsigned short* __restrict__ camH,
    float* __restrict__ O,
    const float* __restrict__ conf, const float* __restrict__ svec)
{
  __shared__ __attribute__((aligned(16))) unsigned short Ah[128][40];
  __shared__ __attribute__((aligned(16))) unsigned short Bh[256][40];

  int bn, bm, bz; swz_xyz(bn, bm, bz);   // grid (8,16,8)
  const int t = threadIdx.x;             // 0..511
  const int lane = t & 63, w = t >> 6;   // 8 waves
  const int wrow = w >> 2, wcol = w & 3; // 2 x 4
  const int lr = lane & 15, lk = (lane >> 4) << 3;

  f32x4 acc[4][4];
#pragma unroll
  for (int m = 0; m < 4; ++m)
#pragma unroll
    for (int n = 0; n < 4; ++n){ f32x4 z = {0.f,0.f,0.f,0.f}; acc[m][n] = z; }

  const unsigned short* Ap = Th   + (size_t)bz*((size_t)NN*DD) + ((size_t)bm*128)*DD;
  const unsigned short* Bp = camH + (size_t)bz*((size_t)MM*DD) + ((size_t)bn*256)*DD;

  const int sr = t >> 2;          // 0..127
  const int sc = (t & 3) * 8;     // 0,8,16,24

  for (int k0 = 0; k0 < DD; k0 += 32){
    __syncthreads();
    *(u16x8*)&Ah[sr][sc] = *(const u16x8*)(Ap + (size_t)sr*DD + k0 + sc);
#pragma unroll
    for (int p = 0; p < 2; ++p){
      int r = sr + 128*p;
      *(u16x8*)&Bh[r][sc] = *(const u16x8*)(Bp + (size_t)r*DD + k0 + sc);
    }
    __syncthreads();

    f16x8 af[4], bf[4];
#pragma unroll
    for (int m = 0; m < 4; ++m) af[m] = *(const f16x8*)&Ah[wrow*64 + m*16 + lr][lk];
#pragma unroll
    for (int n = 0; n < 4; ++n) bf[n] = *(const f16x8*)&Bh[wcol*64 + n*16 + lr][lk];
#pragma unroll
    for (int m = 0; m < 4; ++m)
#pragma unroll
      for (int n = 0; n < 4; ++n)
        acc[m][n] = mfmah(af[m], bf[n], acc[m][n]);
  }

  const int orow0 = bm*128 + wrow*64;
  const int ocol0 = bn*256 + wcol*64;
  const size_t obase = (size_t)bz*((size_t)NN*MM);
#pragma unroll
  for (int m = 0; m < 4; ++m){
#pragma unroll
    for (int n = 0; n < 4; ++n){
      int col  = ocol0 + n*16 + lr;
      float sv = svec[bz*MM + col];
      int row0 = orow0 + m*16 + ((lane >> 4) << 2);
#pragma unroll
      for (int r = 0; r < 4; ++r){
        int row = row0 + r;
        O[obase + (size_t)row*MM + col]
            = conf[bz*NN + row] * (acc[m][n][r] + sv);
      }
    }
  }
}

// ---------------------------------------------------------------------------
// PV GEMM: out[n,e] = sum_m P[n,m]*Vt[e,m].  Block 64(rows) x 256(cols),
// 4 waves 1x4, wave 64x64.  P f16 at lda=2*MM (in-place in scores buffer).
// ---------------------------------------------------------------------------
__global__ __launch_bounds__(256) void gemm_pv(
    const unsigned short* __restrict__ P,
    const unsigned short* __restrict__ V,
    float* __restrict__ O)
{
  __shared__ __attribute__((aligned(16))) unsigned short Ah[64][40];
  __shared__ __attribute__((aligned(16))) unsigned short Bh[256][40];

  int bn, bm, bz; swz_xyz(bn, bm, bz);
  const int t = threadIdx.x;
  const int lane = t & 63, w = t >> 6;
  const int lr = lane & 15, lk = (lane >> 4) << 3;

  f32x4 acc[4][4];
#pragma unroll
  for (int m = 0; m < 4; ++m)
#pragma unroll
    for (int n = 0; n < 4; ++n){ f32x4 z = {0.f,0.f,0.f,0.f}; acc[m][n] = z; }

  const unsigned short* Ap = P + (size_t)bz*((size_t)NN*2*MM) + ((size_t)bm*64)*(2*MM);
  const unsigned short* Bp = V + (size_t)bz*((size_t)DD*MM) + ((size_t)bn*256)*MM;

  const int sr = t >> 2;          // 0..63
  const int sc = (t & 3) * 8;

  for (int k0 = 0; k0 < MM; k0 += 32){
    __syncthreads();
    *(u16x8*)&Ah[sr][sc] = *(const u16x8*)(Ap + (size_t)sr*(2*MM) + k0 + sc);
#pragma unroll
    for (int p = 0; p < 4; ++p){
      int r = sr + 64*p;
      *(u16x8*)&Bh[r][sc] = *(const u16x8*)(Bp + (size_t)r*MM + k0 + sc);
    }
    __syncthreads();

    f16x8 af[4], bf[4];
#pragma unroll
    for (int m = 0; m < 4; ++m) af[m] = *(const f16x8*)&Ah[m*16 + lr][lk];
#pragma unroll
    for (int n = 0; n < 4; ++n) bf[n] = *(const f16x8*)&Bh[w*64 + n*16 + lr][lk];
#pragma unroll
    for (int m = 0; m < 4; ++m)
#pragma unroll
      for (int n = 0; n < 4; ++n)
        acc[m][n] = mfmah(af[m], bf[n], acc[m][n]);
  }

  const int orow0 = bm*64;
  const int ocol0 = bn*256 + w*64;
#pragma unroll
  for (int m = 0; m < 4; ++m){
#pragma unroll
    for (int n = 0; n < 4; ++n){
      int col  = ocol0 + n*16 + lr;
      int row0 = orow0 + m*16 + ((lane >> 4) << 2);
#pragma unroll
      for (int r = 0; r < 4; ++r){
        int row = row0 + r;
        O[(size_t)bz*((size_t)NN*DD) + (size_t)row*DD + col] = acc[m][n][r];
      }
    }
  }
}

// ---------------------------------------------------------------------------
// Row softmax over M=2048, f32 in, f16 out in-place (row's first 4KB)
// ---------------------------------------------------------------------------
__global__ __launch_bounds__(256) void softmax_kernel(float* __restrict__ scores){
  const size_t row = blockIdx.x;
  float* src = scores + row * MM;
  unsigned short* dst = (unsigned short*)scores + row * (size_t)(2*MM);
  const int t = threadIdx.x;

  float4 v0 = ((const float4*)src)[t];
  float4 v1 = ((const float4*)src)[t + 256];

  float mx = fmaxf(fmaxf(fmaxf(v0.x,v0.y), fmaxf(v0.z,v0.w)),
                   fmaxf(fmaxf(v1.x,v1.y), fmaxf(v1.z,v1.w)));
  for (int o = 32; o; o >>= 1) mx = fmaxf(mx, __shfl_xor(mx, o));
  __shared__ float red[4];
  if ((t & 63) == 0) red[t >> 6] = mx;
  __syncthreads();
  mx = fmaxf(fmaxf(red[0], red[1]), fmaxf(red[2], red[3]));

  float e0x = __expf(v0.x - mx), e0y = __expf(v0.y - mx);
  float e0z = __expf(v0.z - mx), e0w = __expf(v0.w - mx);
  float e1x = __expf(v1.x - mx), e1y = __expf(v1.y - mx);
  float e1z = __expf(v1.z - mx), e1w = __expf(v1.w - mx);
  float s = e0x+e0y+e0z+e0w+e1x+e1y+e1z+e1w;
  for (int o = 32; o; o >>= 1) s += __shfl_xor(s, o);
  __syncthreads();
  if ((t & 63) == 0) red[t >> 6] = s;
  __syncthreads();
  float inv = 1.f / (red[0] + red[1] + red[2] + red[3]);

  ushort4 p0; p0.x=f2h(e0x*inv); p0.y=f2h(e0y*inv); p0.z=f2h(e0z*inv); p0.w=f2h(e0w*inv);
  ushort4 p1; p1.x=f2h(e1x*inv); p1.y=f2h(e1y*inv); p1.z=f2h(e1z*inv); p1.w=f2h(e1w*inv);
  ((ushort4*)dst)[t]       = p0;
  ((ushort4*)dst)[t + 256] = p1;
}

// ---------------------------------------------------------------------------
extern "C" void kernel_launch(void* const* d_in, const int* in_sizes, int n_in,
                              void* d_out, int out_size, void* d_ws, size_t ws_size,
                              hipStream_t stream) {
  const float* lidar  = (const float*)d_in[0];   // [B,N,D]
  const float* camera = (const float*)d_in[1];   // [B,M,D]
  const float* lconf  = (const float*)d_in[2];   // [B,N,1]
  // d_in[3] camera_confidence: unused by the reference
  const float* Wq = (const float*)d_in[4];
  const float* bq = (const float*)d_in[5];
  const float* Wk = (const float*)d_in[6];
  // d_in[7] bk: row-constant in scores -> softmax-invariant, dropped
  const float* Wv = (const float*)d_in[8];
  const float* bv = (const float*)d_in[9];
  float* out = (float*)d_out;                    // [B,N,D] f32

  // workspace layout (bytes), total ~185 MB
  char* ws = (char*)d_ws;
  float*          scores = (float*)(ws + 0);                  // [B,N,M] f32 134.2MB (P f16 in-place)
  // transient aliases inside scores region (dead before scores is written):
  unsigned short* liH    = (unsigned short*)(ws + 0);         // [B,N,D] f16 16.8MB
  unsigned short* atH    = (unsigned short*)(ws + 16777216);  // [D,D]   f16 0.5MB
  unsigned short* wvH    = (unsigned short*)(ws + 17301504);  // [D,D]   f16 0.5MB
  float*          c2     = (float*)(ws + 17825792);           // [D]
  // persistent:
  unsigned short* Th     = (unsigned short*)(ws + 134217728); // [B,N,D] f16 16.8MB
  unsigned short* camH   = (unsigned short*)(ws + 150994944); // [B,M,D] f16 16.8MB
  unsigned short* Vt     = (unsigned short*)(ws + 167772160); // [B,D,M] f16 16.8MB
  float*          svec   = (float*)(ws + 184549376);          // [B,M]

  // f32 -> f16 conversions
  cvt16_kernel<<<dim3(2048), 256, 0, stream>>>(camera, camH, BB*MM*DD/4);
  cvt16_kernel<<<dim3(2048), 256, 0, stream>>>(lidar,  liH,  BB*NN*DD/4);
  cvt16_kernel<<<dim3(256),  256, 0, stream>>>(Wv,     wvH,  DD*DD/4);
  at_kernel<<<dim3(16,16), 256, 0, stream>>>(Wq, Wk, atH);
  c2_kernel<<<dim3(2), 256, 0, stream>>>(bq, Wk, c2);
  s_kernel<<<dim3(BB*MM), 64, 0, stream>>>(camera, c2, svec);

  // T = lidar @ At^T  (f16) -> Th
  gemm_h128<0><<<dim3(DD/128, NN/128, BB), 256, 0, stream>>>(
      liH, (long)NN*DD, DD,  atH, 0, DD,
      Th, (long)NN*DD, DD, nullptr);

  // Vt[e,m] = Wv[e,:].cam[m,:] + bv[e]  (f16)
  gemm_h128<1><<<dim3(MM/128, DD/128, BB), 256, 0, stream>>>(
      wvH, 0, DD,  camH, (long)MM*DD, DD,
      Vt, (long)DD*MM, MM, bv);

  // scores = conf * (T @ cam^T + svec)  (f16 inputs, f32 out, 8-wave)
  gemm_scores<<<dim3(MM/256, NN/128, BB), 512, 0, stream>>>(
      Th, camH, scores, lconf, svec);

  // row softmax, P f16 in-place
  softmax_kernel<<<dim3(BB*NN), 256, 0, stream>>>(scores);

  // out = P @ Vt^T  (f16)
  gemm_pv<<<dim3(DD/256, NN/64, BB), 256, 0, stream>>>(
      (const unsigned short*)scores, Vt, out);
}

// Round 9
// 243.363 us; speedup vs baseline: 1.4158x; 1.0223x over previous
//
#include <hip/hip_runtime.h>
#include <hip/hip_bf16.h>

#define BB 8
#define NN 2048
#define MM 2048
#define DD 512

typedef __attribute__((ext_vector_type(8))) _Float16 f16x8;
typedef __attribute__((ext_vector_type(4))) float f32x4;
typedef __attribute__((ext_vector_type(8))) unsigned short u16x8;

__device__ __forceinline__ unsigned short f2h(float x){
  union { _Float16 h; unsigned short u; } cv;
  cv.h = (_Float16)x;           // v_cvt_f16_f32, RTN-even
  return cv.u;
}
__device__ __forceinline__ f32x4 mfmah(f16x8 a, f16x8 b, f32x4 c){
  return __builtin_amdgcn_mfma_f32_16x16x32_f16(a, b, c, 0, 0, 0);
}

// batch->XCD swizzle: flat id f -> bz = f&7 (XCD presumed f%8), bijective
// (requires gridDim.z == 8)
__device__ __forceinline__ void swz_xyz(int& bn, int& bm, int& bz){
  int f = ((int)blockIdx.z * (int)gridDim.y + (int)blockIdx.y) * (int)gridDim.x
        + (int)blockIdx.x;
  bz = f & 7;
  int r = f >> 3;
  bn = r % (int)gridDim.x;
  bm = r / (int)gridDim.x;
}

// ---------------------------------------------------------------------------
// cvt16: f32 -> f16, float4-vectorized, grid-stride
// ---------------------------------------------------------------------------
__global__ __launch_bounds__(256) void cvt16_kernel(const float* __restrict__ in,
    unsigned short* __restrict__ out, int n4){
  int i = blockIdx.x*256 + threadIdx.x;
  const int stride = gridDim.x*256;
  for (; i < n4; i += stride){
    float4 v = ((const float4*)in)[i];
    ushort4 h; h.x=f2h(v.x); h.y=f2h(v.y); h.z=f2h(v.z); h.w=f2h(v.w);
    ((ushort4*)out)[i] = h;
  }
}

// ---------------------------------------------------------------------------
// cam_prep: one pass over camera f32 -> camH f16 AND svec[row] = cam.c2
// 256 threads = 4 waves, one row per wave.  grid = B*M/4.
// ---------------------------------------------------------------------------
__global__ __launch_bounds__(256) void cam_prep(const float* __restrict__ cam,
    const float* __restrict__ c2,
    unsigned short* __restrict__ camH,
    float* __restrict__ svec){
  const int t = threadIdx.x;
  const int l = t & 63;
  const size_t row = (size_t)blockIdx.x*4 + (t >> 6);
  const float4* r4 = (const float4*)(cam + row*DD);
  const float4* c4 = (const float4*)c2;
  float4 v0 = r4[l*2],   v1 = r4[l*2+1];
  float4 a0 = c4[l*2],   a1 = c4[l*2+1];
  float p = v0.x*a0.x + v0.y*a0.y + v0.z*a0.z + v0.w*a0.w
          + v1.x*a1.x + v1.y*a1.y + v1.z*a1.z + v1.w*a1.w;
  for (int o = 32; o; o >>= 1) p += __shfl_xor(p, o);
  if (l == 0) svec[row] = p;
  ushort4 h0; h0.x=f2h(v0.x); h0.y=f2h(v0.y); h0.z=f2h(v0.z); h0.w=f2h(v0.w);
  ushort4 h1; h1.x=f2h(v1.x); h1.y=f2h(v1.y); h1.z=f2h(v1.z); h1.w=f2h(v1.w);
  ushort4* dst = (ushort4*)(camH + row*DD);
  dst[l*2]   = h0;
  dst[l*2+1] = h1;
}

// ---------------------------------------------------------------------------
// K0: At[j][i] = sum_e Wq[e][i] * Wk[e][j], f32 accum, f16 out
// ---------------------------------------------------------------------------
__global__ __launch_bounds__(256) void at_kernel(const float* __restrict__ Wq,
                                                 const float* __restrict__ Wk,
                                                 unsigned short* __restrict__ atH){
  const int i0 = blockIdx.x * 32, j0 = blockIdx.y * 32;
  __shared__ float q_s[32][33];
  __shared__ float k_s[32][33];
  const int t = threadIdx.x;
  const int tx = t & 15, ty = t >> 4;
  float acc[2][2] = {{0.f,0.f},{0.f,0.f}};
  for (int e0 = 0; e0 < DD; e0 += 32){
    __syncthreads();
#pragma unroll
    for (int p = 0; p < 4; ++p){
      int idx = t + 256*p;
      int e = idx >> 5, c = idx & 31;
      q_s[e][c] = Wq[(size_t)(e0+e)*DD + i0 + c];
      k_s[e][c] = Wk[(size_t)(e0+e)*DD + j0 + c];
    }
    __syncthreads();
#pragma unroll 8
    for (int e = 0; e < 32; ++e){
      float q0 = q_s[e][2*tx], q1 = q_s[e][2*tx+1];
      float k0 = k_s[e][2*ty], k1 = k_s[e][2*ty+1];
      acc[0][0] += k0*q0; acc[0][1] += k0*q1;
      acc[1][0] += k1*q0; acc[1][1] += k1*q1;
    }
  }
#pragma unroll
  for (int a = 0; a < 2; ++a)
#pragma unroll
    for (int b = 0; b < 2; ++b)
      atH[(size_t)(j0 + 2*ty + a)*DD + i0 + 2*tx + b] = f2h(acc[a][b]);
}

// c2[d] = sum_e bq[e] * Wk[e][d]
__global__ __launch_bounds__(256) void c2_kernel(const float* __restrict__ bq,
                                                 const float* __restrict__ Wk,
                                                 float* __restrict__ c2){
  int d = blockIdx.x * 256 + threadIdx.x;
  float a = 0.f;
  for (int e = 0; e < DD; ++e) a += bq[e] * Wk[(size_t)e*DD + d];
  c2[d] = a;
}

// ---------------------------------------------------------------------------
// Plain f16 GEMM, BT form: O[row,col] = sum_k A[row,k]*B[col,k], f16 out.
// Block 128x128, 4 waves 2x2, wave 64x64 (4x4 frags of 16x16x32 f16).
// MODE 0: plain.  MODE 1: + bias[row].
// ---------------------------------------------------------------------------
template<int MODE>
__global__ __launch_bounds__(256) void gemm_h128(
    const unsigned short* __restrict__ Ag, long sA, int lda,
    const unsigned short* __restrict__ Bg, long sB, int ldb,
    unsigned short* __restrict__ O, long sO, int ldo,
    const float* __restrict__ bias)
{
  __shared__ __attribute__((aligned(16))) unsigned short Ah[128][40];
  __shared__ __attribute__((aligned(16))) unsigned short Bh[128][40];

  int bn, bm, bz; swz_xyz(bn, bm, bz);
  const int t = threadIdx.x;
  const int lane = t & 63, w = t >> 6;
  const int wrow = w >> 1, wcol = w & 1;
  const int lr = lane & 15, lk = (lane >> 4) << 3;

  f32x4 acc[4][4];
#pragma unroll
  for (int m = 0; m < 4; ++m)
#pragma unroll
    for (int n = 0; n < 4; ++n){ f32x4 z = {0.f,0.f,0.f,0.f}; acc[m][n] = z; }

  const unsigned short* Ap = Ag + (size_t)bz*(size_t)sA + ((size_t)bm*128)*(size_t)lda;
  const unsigned short* Bp = Bg + (size_t)bz*(size_t)sB + ((size_t)bn*128)*(size_t)ldb;

  const int sr = t >> 2;          // 0..63
  const int sc = (t & 3) * 8;

  for (int k0 = 0; k0 < DD; k0 += 32){
    __syncthreads();
#pragma unroll
    for (int p = 0; p < 2; ++p){
      int r = sr + 64*p;
      *(u16x8*)&Ah[r][sc] = *(const u16x8*)(Ap + (size_t)r*lda + k0 + sc);
      *(u16x8*)&Bh[r][sc] = *(const u16x8*)(Bp + (size_t)r*ldb + k0 + sc);
    }
    __syncthreads();

    f16x8 af[4], bf[4];
#pragma unroll
    for (int m = 0; m < 4; ++m) af[m] = *(const f16x8*)&Ah[wrow*64 + m*16 + lr][lk];
#pragma unroll
    for (int n = 0; n < 4; ++n) bf[n] = *(const f16x8*)&Bh[wcol*64 + n*16 + lr][lk];
#pragma unroll
    for (int m = 0; m < 4; ++m)
#pragma unroll
      for (int n = 0; n < 4; ++n)
        acc[m][n] = mfmah(af[m], bf[n], acc[m][n]);
  }

  const int orow = bm*128 + wrow*64;
  const int ocol = bn*128 + wcol*64;
#pragma unroll
  for (int m = 0; m < 4; ++m){
#pragma unroll
    for (int n = 0; n < 4; ++n){
      int col  = ocol + n*16 + lr;
      int row0 = orow + m*16 + ((lane >> 4) << 2);
#pragma unroll
      for (int r = 0; r < 4; ++r){
        int row = row0 + r;
        float v = acc[m][n][r];
        if constexpr (MODE == 1) v += bias[row];
        O[(size_t)bz*(size_t)sO + (size_t)row*ldo + col] = f2h(v);
      }
    }
  }
}

// ---------------------------------------------------------------------------
// scores f16 GEMM: O[row,col] = conf[row]*(sum_k T[row,k]*cam[col,k]+svec[col])
// Block 128(rows) x 256(cols), 8 waves (2 row x 4 col), wave tile 64x64
// (4x4 frags) -> acc 64 VGPR, under the 128-VGPR occupancy cliff.
// ---------------------------------------------------------------------------
__global__ __launch_bounds__(512) void gemm_scores(
    const unsigned short* __restrict__ Th, const unsigned short* __restrict__ camH,
    float* __restrict__ O,
    const float* __restrict__ conf, const float* __restrict__ svec)
{
  __shared__ __attribute__((aligned(16))) unsigned short Ah[128][40];
  __shared__ __attribute__((aligned(16))) unsigned short Bh[256][40];

  int bn, bm, bz; swz_xyz(bn, bm, bz);   // grid (8,16,8)
  const int t = threadIdx.x;             // 0..511
  const int lane = t & 63, w = t >> 6;   // 8 waves
  const int wrow = w >> 2, wcol = w & 3; // 2 x 4
  const int lr = lane & 15, lk = (lane >> 4) << 3;

  f32x4 acc[4][4];
#pragma unroll
  for (int m = 0; m < 4; ++m)
#pragma unroll
    for (int n = 0; n < 4; ++n){ f32x4 z = {0.f,0.f,0.f,0.f}; acc[m][n] = z; }

  const unsigned short* Ap = Th   + (size_t)bz*((size_t)NN*DD) + ((size_t)bm*128)*DD;
  const unsigned short* Bp = camH + (size_t)bz*((size_t)MM*DD) + ((size_t)bn*256)*DD;

  const int sr = t >> 2;          // 0..127
  const int sc = (t & 3) * 8;     // 0,8,16,24

  for (int k0 = 0; k0 < DD; k0 += 32){
    __syncthreads();
    *(u16x8*)&Ah[sr][sc] = *(const u16x8*)(Ap + (size_t)sr*DD + k0 + sc);
#pragma unroll
    for (int p = 0; p < 2; ++p){
      int r = sr + 128*p;
      *(u16x8*)&Bh[r][sc] = *(const u16x8*)(Bp + (size_t)r*DD + k0 + sc);
    }
    __syncthreads();

    f16x8 af[4], bf[4];
#pragma unroll
    for (int m = 0; m < 4; ++m) af[m] = *(const f16x8*)&Ah[wrow*64 + m*16 + lr][lk];
#pragma unroll
    for (int n = 0; n < 4; ++n) bf[n] = *(const f16x8*)&Bh[wcol*64 + n*16 + lr][lk];
#pragma unroll
    for (int m = 0; m < 4; ++m)
#pragma unroll
      for (int n = 0; n < 4; ++n)
        acc[m][n] = mfmah(af[m], bf[n], acc[m][n]);
  }

  const int orow0 = bm*128 + wrow*64;
  const int ocol0 = bn*256 + wcol*64;
  const size_t obase = (size_t)bz*((size_t)NN*MM);
#pragma unroll
  for (int m = 0; m < 4; ++m){
#pragma unroll
    for (int n = 0; n < 4; ++n){
      int col  = ocol0 + n*16 + lr;
      float sv = svec[bz*MM + col];
      int row0 = orow0 + m*16 + ((lane >> 4) << 2);
#pragma unroll
      for (int r = 0; r < 4; ++r){
        int row = row0 + r;
        O[obase + (size_t)row*MM + col]
            = conf[bz*NN + row] * (acc[m][n][r] + sv);
      }
    }
  }
}

// ---------------------------------------------------------------------------
// PV GEMM: out[n,e] = sum_m P[n,m]*Vt[e,m].  Block 64(rows) x 256(cols),
// 8 waves 1x8, wave tile 64x32 (4x2 frags, 32 acc VGPR).  P f16 at
// lda=2*MM (in-place in scores buffer).  R8 post-mortem: 4-wave version
// was grid-capped at 8 waves/CU (25% occ) -> latency-bound; 8 waves
// doubles resident waves at identical LDS/grid/traffic.
// ---------------------------------------------------------------------------
__global__ __launch_bounds__(512) void gemm_pv(
    const unsigned short* __restrict__ P,
    const unsigned short* __restrict__ V,
    float* __restrict__ O)
{
  __shared__ __attribute__((aligned(16))) unsigned short Ah[64][40];
  __shared__ __attribute__((aligned(16))) unsigned short Bh[256][40];

  int bn, bm, bz; swz_xyz(bn, bm, bz);   // grid (2,32,8)
  const int t = threadIdx.x;             // 0..511
  const int lane = t & 63, w = t >> 6;   // 8 waves, 1 row x 8 col tiles
  const int lr = lane & 15, lk = (lane >> 4) << 3;

  f32x4 acc[4][2];
#pragma unroll
  for (int m = 0; m < 4; ++m)
#pragma unroll
    for (int n = 0; n < 2; ++n){ f32x4 z = {0.f,0.f,0.f,0.f}; acc[m][n] = z; }

  const unsigned short* Ap = P + (size_t)bz*((size_t)NN*2*MM) + ((size_t)bm*64)*(2*MM);
  const unsigned short* Bp = V + (size_t)bz*((size_t)DD*MM) + ((size_t)bn*256)*MM;

  for (int k0 = 0; k0 < MM; k0 += 32){
    __syncthreads();
    if (t < 256){
      int sr = t >> 2, sc = (t & 3) * 8;
      *(u16x8*)&Ah[sr][sc] = *(const u16x8*)(Ap + (size_t)sr*(2*MM) + k0 + sc);
    }
#pragma unroll
    for (int p = 0; p < 2; ++p){
      int slot = t + 512*p;
      int r = slot >> 2, sc = (slot & 3) * 8;
      *(u16x8*)&Bh[r][sc] = *(const u16x8*)(Bp + (size_t)r*MM + k0 + sc);
    }
    __syncthreads();

    f16x8 af[4], bf[2];
#pragma unroll
    for (int m = 0; m < 4; ++m) af[m] = *(const f16x8*)&Ah[m*16 + lr][lk];
#pragma unroll
    for (int n = 0; n < 2; ++n) bf[n] = *(const f16x8*)&Bh[w*32 + n*16 + lr][lk];
#pragma unroll
    for (int m = 0; m < 4; ++m)
#pragma unroll
      for (int n = 0; n < 2; ++n)
        acc[m][n] = mfmah(af[m], bf[n], acc[m][n]);
  }

  const int orow0 = bm*64;
  const int ocol0 = bn*256 + w*32;
#pragma unroll
  for (int m = 0; m < 4; ++m){
#pragma unroll
    for (int n = 0; n < 2; ++n){
      int col  = ocol0 + n*16 + lr;
      int row0 = orow0 + m*16 + ((lane >> 4) << 2);
#pragma unroll
      for (int r = 0; r < 4; ++r){
        int row = row0 + r;
        O[(size_t)bz*((size_t)NN*DD) + (size_t)row*DD + col] = acc[m][n][r];
      }
    }
  }
}

// ---------------------------------------------------------------------------
// Row softmax over M=2048, f32 in, f16 out in-place (row's first 4KB)
// ---------------------------------------------------------------------------
__global__ __launch_bounds__(256) void softmax_kernel(float* __restrict__ scores){
  const size_t row = blockIdx.x;
  float* src = scores + row * MM;
  unsigned short* dst = (unsigned short*)scores + row * (size_t)(2*MM);
  const int t = threadIdx.x;

  float4 v0 = ((const float4*)src)[t];
  float4 v1 = ((const float4*)src)[t + 256];

  float mx = fmaxf(fmaxf(fmaxf(v0.x,v0.y), fmaxf(v0.z,v0.w)),
                   fmaxf(fmaxf(v1.x,v1.y), fmaxf(v1.z,v1.w)));
  for (int o = 32; o; o >>= 1) mx = fmaxf(mx, __shfl_xor(mx, o));
  __shared__ float red[4];
  if ((t & 63) == 0) red[t >> 6] = mx;
  __syncthreads();
  mx = fmaxf(fmaxf(red[0], red[1]), fmaxf(red[2], red[3]));

  float e0x = __expf(v0.x - mx), e0y = __expf(v0.y - mx);
  float e0z = __expf(v0.z - mx), e0w = __expf(v0.w - mx);
  float e1x = __expf(v1.x - mx), e1y = __expf(v1.y - mx);
  float e1z = __expf(v1.z - mx), e1w = __expf(v1.w - mx);
  float s = e0x+e0y+e0z+e0w+e1x+e1y+e1z+e1w;
  for (int o = 32; o; o >>= 1) s += __shfl_xor(s, o);
  __syncthreads();
  if ((t & 63) == 0) red[t >> 6] = s;
  __syncthreads();
  float inv = 1.f / (red[0] + red[1] + red[2] + red[3]);

  ushort4 p0; p0.x=f2h(e0x*inv); p0.y=f2h(e0y*inv); p0.z=f2h(e0z*inv); p0.w=f2h(e0w*inv);
  ushort4 p1; p1.x=f2h(e1x*inv); p1.y=f2h(e1y*inv); p1.z=f2h(e1z*inv); p1.w=f2h(e1w*inv);
  ((ushort4*)dst)[t]       = p0;
  ((ushort4*)dst)[t + 256] = p1;
}

// ---------------------------------------------------------------------------
extern "C" void kernel_launch(void* const* d_in, const int* in_sizes, int n_in,
                              void* d_out, int out_size, void* d_ws, size_t ws_size,
                              hipStream_t stream) {
  const float* lidar  = (const float*)d_in[0];   // [B,N,D]
  const float* camera = (const float*)d_in[1];   // [B,M,D]
  const float* lconf  = (const float*)d_in[2];   // [B,N,1]
  // d_in[3] camera_confidence: unused by the reference
  const float* Wq = (const float*)d_in[4];
  const float* bq = (const float*)d_in[5];
  const float* Wk = (const float*)d_in[6];
  // d_in[7] bk: row-constant in scores -> softmax-invariant, dropped
  const float* Wv = (const float*)d_in[8];
  const float* bv = (const float*)d_in[9];
  float* out = (float*)d_out;                    // [B,N,D] f32

  // workspace layout (bytes), total ~185 MB
  char* ws = (char*)d_ws;
  float*          scores = (float*)(ws + 0);                  // [B,N,M] f32 134.2MB (P f16 in-place)
  // transient aliases inside scores region (dead before scores is written):
  unsigned short* liH    = (unsigned short*)(ws + 0);         // [B,N,D] f16 16.8MB
  unsigned short* atH    = (unsigned short*)(ws + 16777216);  // [D,D]   f16 0.5MB
  unsigned short* wvH    = (unsigned short*)(ws + 17301504);  // [D,D]   f16 0.5MB
  float*          c2     = (float*)(ws + 17825792);           // [D]
  // persistent:
  unsigned short* Th     = (unsigned short*)(ws + 134217728); // [B,N,D] f16 16.8MB
  unsigned short* camH   = (unsigned short*)(ws + 150994944); // [B,M,D] f16 16.8MB
  unsigned short* Vt     = (unsigned short*)(ws + 167772160); // [B,D,M] f16 16.8MB
  float*          svec   = (float*)(ws + 184549376);          // [B,M]

  // prep: c2 first (cam_prep consumes it), then fused camera pass
  c2_kernel<<<dim3(2), 256, 0, stream>>>(bq, Wk, c2);
  cam_prep<<<dim3(BB*MM/4), 256, 0, stream>>>(camera, c2, camH, svec);
  cvt16_kernel<<<dim3(2048), 256, 0, stream>>>(lidar,  liH,  BB*NN*DD/4);
  cvt16_kernel<<<dim3(256),  256, 0, stream>>>(Wv,     wvH,  DD*DD/4);
  at_kernel<<<dim3(16,16), 256, 0, stream>>>(Wq, Wk, atH);

  // T = lidar @ At^T  (f16) -> Th
  gemm_h128<0><<<dim3(DD/128, NN/128, BB), 256, 0, stream>>>(
      liH, (long)NN*DD, DD,  atH, 0, DD,
      Th, (long)NN*DD, DD, nullptr);

  // Vt[e,m] = Wv[e,:].cam[m,:] + bv[e]  (f16)
  gemm_h128<1><<<dim3(MM/128, DD/128, BB), 256, 0, stream>>>(
      wvH, 0, DD,  camH, (long)MM*DD, DD,
      Vt, (long)DD*MM, MM, bv);

  // scores = conf * (T @ cam^T + svec)  (f16 inputs, f32 out, 8-wave)
  gemm_scores<<<dim3(MM/256, NN/128, BB), 512, 0, stream>>>(
      Th, camH, scores, lconf, svec);

  // row softmax, P f16 in-place
  softmax_kernel<<<dim3(BB*NN), 256, 0, stream>>>(scores);

  // out = P @ Vt^T  (f16, 8-wave)
  gemm_pv<<<dim3(DD/256, NN/64, BB), 512, 0, stream>>>(
      (const unsigned short*)scores, Vt, out);
}

// Round 10
// 221.328 us; speedup vs baseline: 1.5567x; 1.0996x over previous
//
#include <hip/hip_runtime.h>
#include <hip/hip_bf16.h>

#define BB 8
#define NN 2048
#define MM 2048
#define DD 512

typedef __attribute__((ext_vector_type(8))) _Float16 f16x8;
typedef __attribute__((ext_vector_type(4))) float f32x4;
typedef __attribute__((ext_vector_type(8))) unsigned short u16x8;

__device__ __forceinline__ unsigned short f2h(float x){
  union { _Float16 h; unsigned short u; } cv;
  cv.h = (_Float16)x;           // v_cvt_f16_f32, RTN-even
  return cv.u;
}
__device__ __forceinline__ f32x4 mfmah(f16x8 a, f16x8 b, f32x4 c){
  return __builtin_amdgcn_mfma_f32_16x16x32_f16(a, b, c, 0, 0, 0);
}

// async global->LDS, 16B per lane; LDS dest is wave-uniform base + lane*16
#define GLD16(gp, lp) __builtin_amdgcn_global_load_lds( \
    (const __attribute__((address_space(1))) void*)(gp), \
    (__attribute__((address_space(3))) void*)(lp), 16, 0, 0)

// wait until <= n vector-memory ops outstanding (lgkm/exp not waited)
#define WAITVM(n) __builtin_amdgcn_s_waitcnt(0xF70 | (n))

// batch->XCD swizzle: flat id f -> bz = f&7 (XCD presumed f%8), bijective
// (requires gridDim.z == 8)
__device__ __forceinline__ void swz_xyz(int& bn, int& bm, int& bz){
  int f = ((int)blockIdx.z * (int)gridDim.y + (int)blockIdx.y) * (int)gridDim.x
        + (int)blockIdx.x;
  bz = f & 7;
  int r = f >> 3;
  bn = r % (int)gridDim.x;
  bm = r / (int)gridDim.x;
}

// ---------------------------------------------------------------------------
// cvt16: f32 -> f16, float4-vectorized, grid-stride
// ---------------------------------------------------------------------------
__global__ __launch_bounds__(256) void cvt16_kernel(const float* __restrict__ in,
    unsigned short* __restrict__ out, int n4){
  int i = blockIdx.x*256 + threadIdx.x;
  const int stride = gridDim.x*256;
  for (; i < n4; i += stride){
    float4 v = ((const float4*)in)[i];
    ushort4 h; h.x=f2h(v.x); h.y=f2h(v.y); h.z=f2h(v.z); h.w=f2h(v.w);
    ((ushort4*)out)[i] = h;
  }
}

// ---------------------------------------------------------------------------
// cam_prep: one pass over camera f32 -> camH f16 AND svec[row] = cam.c2
// 256 threads = 4 waves, one row per wave.  grid = B*M/4.
// ---------------------------------------------------------------------------
__global__ __launch_bounds__(256) void cam_prep(const float* __restrict__ cam,
    const float* __restrict__ c2,
    unsigned short* __restrict__ camH,
    float* __restrict__ svec){
  const int t = threadIdx.x;
  const int l = t & 63;
  const size_t row = (size_t)blockIdx.x*4 + (t >> 6);
  const float4* r4 = (const float4*)(cam + row*DD);
  const float4* c4 = (const float4*)c2;
  float4 v0 = r4[l*2],   v1 = r4[l*2+1];
  float4 a0 = c4[l*2],   a1 = c4[l*2+1];
  float p = v0.x*a0.x + v0.y*a0.y + v0.z*a0.z + v0.w*a0.w
          + v1.x*a1.x + v1.y*a1.y + v1.z*a1.z + v1.w*a1.w;
  for (int o = 32; o; o >>= 1) p += __shfl_xor(p, o);
  if (l == 0) svec[row] = p;
  ushort4 h0; h0.x=f2h(v0.x); h0.y=f2h(v0.y); h0.z=f2h(v0.z); h0.w=f2h(v0.w);
  ushort4 h1; h1.x=f2h(v1.x); h1.y=f2h(v1.y); h1.z=f2h(v1.z); h1.w=f2h(v1.w);
  ushort4* dst = (ushort4*)(camH + row*DD);
  dst[l*2]   = h0;
  dst[l*2+1] = h1;
}

// ---------------------------------------------------------------------------
// K0: At[j][i] = sum_e Wq[e][i] * Wk[e][j], f32 accum, f16 out
// ---------------------------------------------------------------------------
__global__ __launch_bounds__(256) void at_kernel(const float* __restrict__ Wq,
                                                 const float* __restrict__ Wk,
                                                 unsigned short* __restrict__ atH){
  const int i0 = blockIdx.x * 32, j0 = blockIdx.y * 32;
  __shared__ float q_s[32][33];
  __shared__ float k_s[32][33];
  const int t = threadIdx.x;
  const int tx = t & 15, ty = t >> 4;
  float acc[2][2] = {{0.f,0.f},{0.f,0.f}};
  for (int e0 = 0; e0 < DD; e0 += 32){
    __syncthreads();
#pragma unroll
    for (int p = 0; p < 4; ++p){
      int idx = t + 256*p;
      int e = idx >> 5, c = idx & 31;
      q_s[e][c] = Wq[(size_t)(e0+e)*DD + i0 + c];
      k_s[e][c] = Wk[(size_t)(e0+e)*DD + j0 + c];
    }
    __syncthreads();
#pragma unroll 8
    for (int e = 0; e < 32; ++e){
      float q0 = q_s[e][2*tx], q1 = q_s[e][2*tx+1];
      float k0 = k_s[e][2*ty], k1 = k_s[e][2*ty+1];
      acc[0][0] += k0*q0; acc[0][1] += k0*q1;
      acc[1][0] += k1*q0; acc[1][1] += k1*q1;
    }
  }
#pragma unroll
  for (int a = 0; a < 2; ++a)
#pragma unroll
    for (int b = 0; b < 2; ++b)
      atH[(size_t)(j0 + 2*ty + a)*DD + i0 + 2*tx + b] = f2h(acc[a][b]);
}

// c2[d] = sum_e bq[e] * Wk[e][d]
__global__ __launch_bounds__(256) void c2_kernel(const float* __restrict__ bq,
                                                 const float* __restrict__ Wk,
                                                 float* __restrict__ c2){
  int d = blockIdx.x * 256 + threadIdx.x;
  float a = 0.f;
  for (int e = 0; e < DD; ++e) a += bq[e] * Wk[(size_t)e*DD + d];
  c2[d] = a;
}

// ---------------------------------------------------------------------------
// Plain f16 GEMM, BT form: O[row,col] = sum_k A[row,k]*B[col,k], f16 out.
// Block 128x128, 4 waves 2x2, wave 64x64 (4x4 frags of 16x16x32 f16).
// MODE 0: plain.  MODE 1: + bias[row].
// ---------------------------------------------------------------------------
template<int MODE>
__global__ __launch_bounds__(256) void gemm_h128(
    const unsigned short* __restrict__ Ag, long sA, int lda,
    const unsigned short* __restrict__ Bg, long sB, int ldb,
    unsigned short* __restrict__ O, long sO, int ldo,
    const float* __restrict__ bias)
{
  __shared__ __attribute__((aligned(16))) unsigned short Ah[128][40];
  __shared__ __attribute__((aligned(16))) unsigned short Bh[128][40];

  int bn, bm, bz; swz_xyz(bn, bm, bz);
  const int t = threadIdx.x;
  const int lane = t & 63, w = t >> 6;
  const int wrow = w >> 1, wcol = w & 1;
  const int lr = lane & 15, lk = (lane >> 4) << 3;

  f32x4 acc[4][4];
#pragma unroll
  for (int m = 0; m < 4; ++m)
#pragma unroll
    for (int n = 0; n < 4; ++n){ f32x4 z = {0.f,0.f,0.f,0.f}; acc[m][n] = z; }

  const unsigned short* Ap = Ag + (size_t)bz*(size_t)sA + ((size_t)bm*128)*(size_t)lda;
  const unsigned short* Bp = Bg + (size_t)bz*(size_t)sB + ((size_t)bn*128)*(size_t)ldb;

  const int sr = t >> 2;          // 0..63
  const int sc = (t & 3) * 8;

  for (int k0 = 0; k0 < DD; k0 += 32){
    __syncthreads();
#pragma unroll
    for (int p = 0; p < 2; ++p){
      int r = sr + 64*p;
      *(u16x8*)&Ah[r][sc] = *(const u16x8*)(Ap + (size_t)r*lda + k0 + sc);
      *(u16x8*)&Bh[r][sc] = *(const u16x8*)(Bp + (size_t)r*ldb + k0 + sc);
    }
    __syncthreads();

    f16x8 af[4], bf[4];
#pragma unroll
    for (int m = 0; m < 4; ++m) af[m] = *(const f16x8*)&Ah[wrow*64 + m*16 + lr][lk];
#pragma unroll
    for (int n = 0; n < 4; ++n) bf[n] = *(const f16x8*)&Bh[wcol*64 + n*16 + lr][lk];
#pragma unroll
    for (int m = 0; m < 4; ++m)
#pragma unroll
      for (int n = 0; n < 4; ++n)
        acc[m][n] = mfmah(af[m], bf[n], acc[m][n]);
  }

  const int orow = bm*128 + wrow*64;
  const int ocol = bn*128 + wcol*64;
#pragma unroll
  for (int m = 0; m < 4; ++m){
#pragma unroll
    for (int n = 0; n < 4; ++n){
      int col  = ocol + n*16 + lr;
      int row0 = orow + m*16 + ((lane >> 4) << 2);
#pragma unroll
      for (int r = 0; r < 4; ++r){
        int row = row0 + r;
        float v = acc[m][n][r];
        if constexpr (MODE == 1) v += bias[row];
        O[(size_t)bz*(size_t)sO + (size_t)row*ldo + col] = f2h(v);
      }
    }
  }
}

// ---------------------------------------------------------------------------
// scores f16 GEMM: O[row,col] = conf[row]*(sum_k T[row,k]*cam[col,k]+svec[col])
// Block 128(rows) x 256(cols), 8 waves (2 row x 4 col), wave tile 64x64
// (4x4 frags) -> acc 64 VGPR, under the 128-VGPR occupancy cliff.
// ---------------------------------------------------------------------------
__global__ __launch_bounds__(512) void gemm_scores(
    const unsigned short* __restrict__ Th, const unsigned short* __restrict__ camH,
    float* __restrict__ O,
    const float* __restrict__ conf, const float* __restrict__ svec)
{
  __shared__ __attribute__((aligned(16))) unsigned short Ah[128][40];
  __shared__ __attribute__((aligned(16))) unsigned short Bh[256][40];

  int bn, bm, bz; swz_xyz(bn, bm, bz);   // grid (8,16,8)
  const int t = threadIdx.x;             // 0..511
  const int lane = t & 63, w = t >> 6;   // 8 waves
  const int wrow = w >> 2, wcol = w & 3; // 2 x 4
  const int lr = lane & 15, lk = (lane >> 4) << 3;

  f32x4 acc[4][4];
#pragma unroll
  for (int m = 0; m < 4; ++m)
#pragma unroll
    for (int n = 0; n < 4; ++n){ f32x4 z = {0.f,0.f,0.f,0.f}; acc[m][n] = z; }

  const unsigned short* Ap = Th   + (size_t)bz*((size_t)NN*DD) + ((size_t)bm*128)*DD;
  const unsigned short* Bp = camH + (size_t)bz*((size_t)MM*DD) + ((size_t)bn*256)*DD;

  const int sr = t >> 2;          // 0..127
  const int sc = (t & 3) * 8;     // 0,8,16,24

  for (int k0 = 0; k0 < DD; k0 += 32){
    __syncthreads();
    *(u16x8*)&Ah[sr][sc] = *(const u16x8*)(Ap + (size_t)sr*DD + k0 + sc);
#pragma unroll
    for (int p = 0; p < 2; ++p){
      int r = sr + 128*p;
      *(u16x8*)&Bh[r][sc] = *(const u16x8*)(Bp + (size_t)r*DD + k0 + sc);
    }
    __syncthreads();

    f16x8 af[4], bf[4];
#pragma unroll
    for (int m = 0; m < 4; ++m) af[m] = *(const f16x8*)&Ah[wrow*64 + m*16 + lr][lk];
#pragma unroll
    for (int n = 0; n < 4; ++n) bf[n] = *(const f16x8*)&Bh[wcol*64 + n*16 + lr][lk];
#pragma unroll
    for (int m = 0; m < 4; ++m)
#pragma unroll
      for (int n = 0; n < 4; ++n)
        acc[m][n] = mfmah(af[m], bf[n], acc[m][n]);
  }

  const int orow0 = bm*128 + wrow*64;
  const int ocol0 = bn*256 + wcol*64;
  const size_t obase = (size_t)bz*((size_t)NN*MM);
#pragma unroll
  for (int m = 0; m < 4; ++m){
#pragma unroll
    for (int n = 0; n < 4; ++n){
      int col  = ocol0 + n*16 + lr;
      float sv = svec[bz*MM + col];
      int row0 = orow0 + m*16 + ((lane >> 4) << 2);
#pragma unroll
      for (int r = 0; r < 4; ++r){
        int row = row0 + r;
        O[obase + (size_t)row*MM + col]
            = conf[bz*NN + row] * (acc[m][n][r] + sv);
      }
    }
  }
}

// ---------------------------------------------------------------------------
// PV GEMM v2: out[n,e] = sum_m P[n,m]*Vt[e,m].  Block 64(n) x 256(e),
// 8 waves 1x8, wave 64n x 32e (4x2 frags), BK=64 (32 iters).
// 2-phase pipeline (guide T3 minimum template): double-buffered linear LDS
// staged via global_load_lds w16; issue next tile's DMA BEFORE computing
// current; ONE raw s_barrier + vmcnt(0) per iter (DMA flies under compute).
// XOR chunk swizzle pc = lc ^ (row&7) applied on BOTH the pre-swizzled
// per-lane global source and the fragment reads (T21) -> b128 reads spread
// over all 8 bank-quads.
// ---------------------------------------------------------------------------
__global__ __launch_bounds__(512) void gemm_pv(
    const unsigned short* __restrict__ P,
    const unsigned short* __restrict__ V,
    float* __restrict__ O)
{
  __shared__ unsigned short Ah[2][64][64];    // 16 KB
  __shared__ unsigned short Bh[2][256][64];   // 64 KB

  int bn, bm, bz; swz_xyz(bn, bm, bz);   // grid (2,32,8)
  const int t = threadIdx.x;             // 0..511
  const int lane = t & 63, w = t >> 6;   // 8 waves
  const int lr = lane & 15, lc0 = lane >> 4;

  const unsigned short* Ap = P + (size_t)bz*((size_t)NN*2*MM) + ((size_t)bm*64)*(2*MM);
  const unsigned short* Bp = V + (size_t)bz*((size_t)DD*MM) + ((size_t)bn*256)*MM;

  // staging: wave w stages A rows 8w..8w+7 (1 instr) and B rows 32w..32w+31
  // (4 instrs).  lane i -> row base+(i>>3), phys chunk i&7; its global source
  // is logical chunk (i&7)^(row&7)  (inverse swizzle; XOR is an involution).
  const int arow = 8*w + (lane >> 3);
  const int alc  = (lane & 7) ^ (arow & 7);
  const unsigned short* gA = Ap + (size_t)arow*(2*MM) + alc*8;
  const int brow = 32*w + (lane >> 3);
  const int blc  = (lane & 7) ^ (brow & 7);   // same for all 4 B instrs (rows +8k)
  const unsigned short* gB = Bp + (size_t)brow*MM + blc*8;

#define PV_STAGE(bufi, kofs) do {                                   \
    GLD16(gA + (kofs),                 &Ah[bufi][8*w][0]);          \
    GLD16(gB + (kofs),                 &Bh[bufi][32*w     ][0]);    \
    GLD16(gB + (kofs) + (size_t)8*MM,  &Bh[bufi][32*w +  8][0]);    \
    GLD16(gB + (kofs) + (size_t)16*MM, &Bh[bufi][32*w + 16][0]);    \
    GLD16(gB + (kofs) + (size_t)24*MM, &Bh[bufi][32*w + 24][0]);    \
  } while(0)

  f32x4 acc[4][2];
#pragma unroll
  for (int m = 0; m < 4; ++m)
#pragma unroll
    for (int n = 0; n < 2; ++n){ f32x4 z = {0.f,0.f,0.f,0.f}; acc[m][n] = z; }

  // prologue: stage tile 0, wait, sync
  PV_STAGE(0, 0);
  WAITVM(0);
  __builtin_amdgcn_s_barrier();
  __builtin_amdgcn_sched_barrier(0);

  for (int tt = 0; tt < 32; ++tt){
    const int buf = tt & 1;
    if (tt < 31) PV_STAGE(buf^1, (size_t)(tt+1)*64);  // overwrites buffer
                                                      // computed at tt-1; all
                                                      // waves passed tt-1's
                                                      // end barrier -> safe
    f16x8 af[4][2], bf[2][2];
#pragma unroll
    for (int m = 0; m < 4; ++m){
      int row = m*16 + lr;
#pragma unroll
      for (int ks = 0; ks < 2; ++ks){
        int pc = (ks*4 + lc0) ^ (row & 7);
        af[m][ks] = *(const f16x8*)&Ah[buf][row][pc*8];
      }
    }
#pragma unroll
    for (int n = 0; n < 2; ++n){
      int row = w*32 + n*16 + lr;
#pragma unroll
      for (int ks = 0; ks < 2; ++ks){
        int pc = (ks*4 + lc0) ^ (row & 7);
        bf[n][ks] = *(const f16x8*)&Bh[buf][row][pc*8];
      }
    }
    __builtin_amdgcn_s_setprio(1);
#pragma unroll
    for (int m = 0; m < 4; ++m)
#pragma unroll
      for (int n = 0; n < 2; ++n){
        acc[m][n] = mfmah(af[m][0], bf[n][0], acc[m][n]);
        acc[m][n] = mfmah(af[m][1], bf[n][1], acc[m][n]);
      }
    __builtin_amdgcn_s_setprio(0);

    WAITVM(0);                          // this iter's DMA landed (flew under
    __builtin_amdgcn_s_barrier();       // the MFMA phase, not serialized)
    __builtin_amdgcn_sched_barrier(0);
  }
#undef PV_STAGE

  const int orow0 = bm*64;
  const int ocol0 = bn*256 + w*32;
#pragma unroll
  for (int m = 0; m < 4; ++m){
#pragma unroll
    for (int n = 0; n < 2; ++n){
      int col  = ocol0 + n*16 + lr;
      int row0 = orow0 + m*16 + ((lane >> 4) << 2);
#pragma unroll
      for (int r = 0; r < 4; ++r){
        int row = row0 + r;
        O[(size_t)bz*((size_t)NN*DD) + (size_t)row*DD + col] = acc[m][n][r];
      }
    }
  }
}

// ---------------------------------------------------------------------------
// Row softmax over M=2048, f32 in, f16 out in-place (row's first 4KB)
// ---------------------------------------------------------------------------
__global__ __launch_bounds__(256) void softmax_kernel(float* __restrict__ scores){
  const size_t row = blockIdx.x;
  float* src = scores + row * MM;
  unsigned short* dst = (unsigned short*)scores + row * (size_t)(2*MM);
  const int t = threadIdx.x;

  float4 v0 = ((const float4*)src)[t];
  float4 v1 = ((const float4*)src)[t + 256];

  float mx = fmaxf(fmaxf(fmaxf(v0.x,v0.y), fmaxf(v0.z,v0.w)),
                   fmaxf(fmaxf(v1.x,v1.y), fmaxf(v1.z,v1.w)));
  for (int o = 32; o; o >>= 1) mx = fmaxf(mx, __shfl_xor(mx, o));
  __shared__ float red[4];
  if ((t & 63) == 0) red[t >> 6] = mx;
  __syncthreads();
  mx = fmaxf(fmaxf(red[0], red[1]), fmaxf(red[2], red[3]));

  float e0x = __expf(v0.x - mx), e0y = __expf(v0.y - mx);
  float e0z = __expf(v0.z - mx), e0w = __expf(v0.w - mx);
  float e1x = __expf(v1.x - mx), e1y = __expf(v1.y - mx);
  float e1z = __expf(v1.z - mx), e1w = __expf(v1.w - mx);
  float s = e0x+e0y+e0z+e0w+e1x+e1y+e1z+e1w;
  for (int o = 32; o; o >>= 1) s += __shfl_xor(s, o);
  __syncthreads();
  if ((t & 63) == 0) red[t >> 6] = s;
  __syncthreads();
  float inv = 1.f / (red[0] + red[1] + red[2] + red[3]);

  ushort4 p0; p0.x=f2h(e0x*inv); p0.y=f2h(e0y*inv); p0.z=f2h(e0z*inv); p0.w=f2h(e0w*inv);
  ushort4 p1; p1.x=f2h(e1x*inv); p1.y=f2h(e1y*inv); p1.z=f2h(e1z*inv); p1.w=f2h(e1w*inv);
  ((ushort4*)dst)[t]       = p0;
  ((ushort4*)dst)[t + 256] = p1;
}

// ---------------------------------------------------------------------------
extern "C" void kernel_launch(void* const* d_in, const int* in_sizes, int n_in,
                              void* d_out, int out_size, void* d_ws, size_t ws_size,
                              hipStream_t stream) {
  const float* lidar  = (const float*)d_in[0];   // [B,N,D]
  const float* camera = (const float*)d_in[1];   // [B,M,D]
  const float* lconf  = (const float*)d_in[2];   // [B,N,1]
  // d_in[3] camera_confidence: unused by the reference
  const float* Wq = (const float*)d_in[4];
  const float* bq = (const float*)d_in[5];
  const float* Wk = (const float*)d_in[6];
  // d_in[7] bk: row-constant in scores -> softmax-invariant, dropped
  const float* Wv = (const float*)d_in[8];
  const float* bv = (const float*)d_in[9];
  float* out = (float*)d_out;                    // [B,N,D] f32

  // workspace layout (bytes), total ~185 MB
  char* ws = (char*)d_ws;
  float*          scores = (float*)(ws + 0);                  // [B,N,M] f32 134.2MB (P f16 in-place)
  // transient aliases inside scores region (dead before scores is written):
  unsigned short* liH    = (unsigned short*)(ws + 0);         // [B,N,D] f16 16.8MB
  unsigned short* atH    = (unsigned short*)(ws + 16777216);  // [D,D]   f16 0.5MB
  unsigned short* wvH    = (unsigned short*)(ws + 17301504);  // [D,D]   f16 0.5MB
  float*          c2     = (float*)(ws + 17825792);           // [D]
  // persistent:
  unsigned short* Th     = (unsigned short*)(ws + 134217728); // [B,N,D] f16 16.8MB
  unsigned short* camH   = (unsigned short*)(ws + 150994944); // [B,M,D] f16 16.8MB
  unsigned short* Vt     = (unsigned short*)(ws + 167772160); // [B,D,M] f16 16.8MB
  float*          svec   = (float*)(ws + 184549376);          // [B,M]

  // prep: c2 first (cam_prep consumes it), then fused camera pass
  c2_kernel<<<dim3(2), 256, 0, stream>>>(bq, Wk, c2);
  cam_prep<<<dim3(BB*MM/4), 256, 0, stream>>>(camera, c2, camH, svec);
  cvt16_kernel<<<dim3(2048), 256, 0, stream>>>(lidar,  liH,  BB*NN*DD/4);
  cvt16_kernel<<<dim3(256),  256, 0, stream>>>(Wv,     wvH,  DD*DD/4);
  at_kernel<<<dim3(16,16), 256, 0, stream>>>(Wq, Wk, atH);

  // T = lidar @ At^T  (f16) -> Th
  gemm_h128<0><<<dim3(DD/128, NN/128, BB), 256, 0, stream>>>(
      liH, (long)NN*DD, DD,  atH, 0, DD,
      Th, (long)NN*DD, DD, nullptr);

  // Vt[e,m] = Wv[e,:].cam[m,:] + bv[e]  (f16)
  gemm_h128<1><<<dim3(MM/128, DD/128, BB), 256, 0, stream>>>(
      wvH, 0, DD,  camH, (long)MM*DD, DD,
      Vt, (long)DD*MM, MM, bv);

  // scores = conf * (T @ cam^T + svec)  (f16 inputs, f32 out, 8-wave)
  gemm_scores<<<dim3(MM/256, NN/128, BB), 512, 0, stream>>>(
      Th, camH, scores, lconf, svec);

  // row softmax, P f16 in-place
  softmax_kernel<<<dim3(BB*NN), 256, 0, stream>>>(scores);

  // out = P @ Vt^T  (f16, 8-wave, 2-phase pipelined)
  gemm_pv<<<dim3(DD/256, NN/64, BB), 512, 0, stream>>>(
      (const unsigned short*)scores, Vt, out);
}